// Round 1
// baseline (800.297 us; speedup 1.0000x reference)
//
#include <hip/hip_runtime.h>

#define S_  2048
#define HD_ 64
#define NH_ 8

// ---- async global->LDS (16B per lane; LDS dst = wave-uniform base + lane*16) ----
__device__ __forceinline__ void gl_lds16(void* lds, const void* g){
  __builtin_amdgcn_global_load_lds(
      (const __attribute__((address_space(1))) void*)g,
      (__attribute__((address_space(3))) void*)lds, 16, 0, 0);
}

// 2nd smallest of 4 == 3rd largest counting multiplicity (matches top_k[-1] + >= semantics)
__device__ __forceinline__ float snd_smallest4(float a, float b, float c, float d){
  float lo1 = fminf(a,b), hi1 = fmaxf(a,b);
  float lo2 = fminf(c,d), hi2 = fmaxf(c,d);
  return fminf(fmaxf(lo1,lo2), fminf(hi1,hi2));
}

// =================== QKV GEMM: x(4096x512) @ w(512x1536) -> Q/Kt/V ===================
__global__ __launch_bounds__(256)
void qkv_kernel(const float* __restrict__ x, const float* __restrict__ wqkv,
                const float* __restrict__ bqkv,
                float* __restrict__ Q, float* __restrict__ Kt, float* __restrict__ V)
{
  __shared__ __align__(16) float Al[64][36];
  __shared__ __align__(16) float Bl[32][128];
  const int tid = threadIdx.x;
  const int tx = tid & 15, ty = tid >> 4;
  const int m0 = blockIdx.x * 64, n0 = blockIdx.y * 128;

  float acc[4][8];
#pragma unroll
  for (int i=0;i<4;i++)
#pragma unroll
    for (int j=0;j<8;j++) acc[i][j] = 0.f;

  float4 ra[2], rb[4];
  auto gload = [&](int kc){
#pragma unroll
    for (int p=0;p<2;p++){
      int e = tid + (p<<8);
      int row = e >> 3, kq = (e & 7) << 2;
      ra[p] = *(const float4*)&x[(size_t)(m0+row)*512 + kc + kq];
    }
#pragma unroll
    for (int p=0;p<4;p++){
      int e = tid + (p<<8);
      int kr = e >> 5, nq = (e & 31) << 2;
      rb[p] = *(const float4*)&wqkv[(size_t)(kc+kr)*1536 + n0 + nq];
    }
  };

  gload(0);
  for (int kc=0; kc<512; kc+=32){
    __syncthreads();
#pragma unroll
    for (int p=0;p<2;p++){
      int e = tid + (p<<8);
      int row = e>>3, kq = (e&7)<<2;
      *(float4*)&Al[row][kq] = ra[p];
    }
#pragma unroll
    for (int p=0;p<4;p++){
      int e = tid + (p<<8);
      int kr = e>>5, nq = (e&31)<<2;
      *(float4*)&Bl[kr][nq] = rb[p];
    }
    __syncthreads();
    if (kc < 480) gload(kc+32);
#pragma unroll
    for (int kk=0; kk<32; ++kk){
      float a[4], b[8];
#pragma unroll
      for (int i=0;i<4;i++) a[i] = Al[ty + (i<<4)][kk];
#pragma unroll
      for (int j=0;j<8;j++) b[j] = Bl[kk][tx + (j<<4)];
#pragma unroll
      for (int i=0;i<4;i++)
#pragma unroll
        for (int j=0;j<8;j++) acc[i][j] = fmaf(a[i], b[j], acc[i][j]);
    }
  }

#pragma unroll
  for (int i=0;i<4;i++){
    int m = m0 + ty + (i<<4);
    int bb = m >> 11, s = m & 2047;
#pragma unroll
    for (int j=0;j<8;j++){
      int n = n0 + tx + (j<<4);
      float v = acc[i][j] + bqkv[n];
      if (n < 512){
        int h = n >> 6, d = n & 63;
        Q[(((size_t)bb*NH_ + h)*S_ + s)*HD_ + d] = v;
      } else if (n < 1024){
        int nn = n - 512; int h = nn >> 6, d = nn & 63;
        Kt[(((size_t)bb*NH_ + h)*HD_ + d)*S_ + s] = v;   // transposed per head
      } else {
        int nn = n - 1024; int h = nn >> 6, d = nn & 63;
        V[(((size_t)bb*NH_ + h)*S_ + s)*HD_ + d] = v;
      }
    }
  }
}

// =================== fi = sigmoid(mean_d q)  (key-position gate) ===================
__global__ __launch_bounds__(256)
void fi_kernel(const float* __restrict__ Q, float* __restrict__ FI)
{
  int row = blockIdx.x*4 + (threadIdx.x >> 6);   // row = bh*S + s, 0..32767
  int l = threadIdx.x & 63;
  float v = Q[(size_t)row*HD_ + l];
#pragma unroll
  for (int sh=1; sh<64; sh<<=1) v += __shfl_xor(v, sh);
  if (l == 0){
    float mean = v * (1.0f/64.0f);
    FI[row] = 1.0f / (1.0f + expf(-mean));
  }
}

// =================== fused attention: scores in regs, topk mask, softmax, attn store, sparse attn@v ===================
__global__ __launch_bounds__(256, 2)
void attn_kernel(const float* __restrict__ Q, const float* __restrict__ Kt,
                 const float* __restrict__ V, const float* __restrict__ FI,
                 float* __restrict__ attn, float* __restrict__ AO)
{
  __shared__ __align__(16) float qs[16*64];
  __shared__ __align__(16) float kbuf[2][4*S_];
  __shared__ float diag[16][24];
  __shared__ float wtop[4][16][5];
  __shared__ float wsum[4][16];
  __shared__ float rstat[4][16];   // 0 thr_g / denom, 1 rowmax, 2 t_b, 3 t_a
  __shared__ int   scnt[16];
  __shared__ int   ssc[16][32];
  __shared__ float ssp[16][32];

  const int tid  = threadIdx.x;
  const int w    = tid >> 6, l = tid & 63;
  const int head = blockIdx.x >> 7;
  const int r0   = (blockIdx.x & 127) << 4;
  const int cbase = w << 9;
  const int cl    = cbase + l;       // this lane's base column; owns cols cl + 64*m, m=0..7

  if (tid < 16) scnt[tid] = 0;

  { // stage q rows, pre-scaled by 1/sqrt(HD)=0.125 (exact pow2)
    const float4* qg = (const float4*)(Q + ((size_t)head*S_ + r0)*HD_);
    float4 q4 = qg[tid];
    q4.x *= 0.125f; q4.y *= 0.125f; q4.z *= 0.125f; q4.w *= 0.125f;
    ((float4*)qs)[tid] = q4;
  }

  const float* ktb = Kt + (size_t)head*HD_*S_;
  auto load_group = [&](int g, int buf){   // 32 KB = Kt[4 d][2048 s], wave-chunked
    const char* src = (const char*)(ktb + (size_t)g*4*S_);
    char* dst = (char*)&kbuf[buf][0];
    int wb = w << 13;
#pragma unroll
    for (int i=0;i<8;i++){
      int off = wb + (i<<10);
      gl_lds16(dst + off, src + off + (l<<4));
    }
  };
  load_group(0, 0);

  float acc[16][8];
#pragma unroll
  for (int r=0;r<16;r++)
#pragma unroll
    for (int m=0;m<8;m++) acc[r][m] = 0.f;

  // ---- phase 1: scores (fp32 FMA, double-buffered K staging) ----
  for (int g=0; g<16; ++g){
    __syncthreads();                       // drains vmcnt -> kbuf[g&1] ready, prev buf free
    if (g < 15) load_group(g+1, (g+1)&1);
    const float* kb = &kbuf[g&1][0];
    float kv[4][8];
#pragma unroll
    for (int dd=0;dd<4;dd++)
#pragma unroll
      for (int m=0;m<8;m++)
        kv[dd][m] = kb[dd*S_ + cl + (m<<6)];
#pragma unroll
    for (int r=0;r<16;r++){
      float4 q4 = *(const float4*)&qs[(r<<6) + (g<<2)];
#pragma unroll
      for (int m=0;m<8;m++){
        float t0 = fmaf(q4.x, kv[0][m], acc[r][m]);
        t0 = fmaf(q4.y, kv[1][m], t0);
        t0 = fmaf(q4.z, kv[2][m], t0);
        acc[r][m] = fmaf(q4.w, kv[3][m], t0);
      }
    }
  }

  // ---- phase 2: diag extract + per-wave top5 (exact multiplicity) ----
  const int Lo = (r0 >= 4) ? (r0 - 4) : 0;
  int dmv  = Lo - cl;
  int m0i  = (dmv > 0) ? ((dmv + 63) >> 6) : 0;
  int didx = cl + (m0i << 6) - Lo;
  bool dvalid = (m0i < 8) && ((unsigned)didx < 24u);

#pragma unroll
  for (int r=0;r<16;r++){
    float dv = acc[r][0];
#pragma unroll
    for (int mm=1;mm<8;mm++) dv = (m0i==mm) ? acc[r][mm] : dv;
    if (dvalid) diag[r][didx] = dv;

    float srt[8];
#pragma unroll
    for (int m=0;m<8;m++) srt[m] = acc[r][m];
    // Batcher odd-even merge sort, descending (19 CE)
#define CE(i,j){ float mx_=fmaxf(srt[i],srt[j]); float mn_=fminf(srt[i],srt[j]); srt[i]=mx_; srt[j]=mn_; }
    CE(0,1) CE(2,3) CE(4,5) CE(6,7)
    CE(0,2) CE(1,3) CE(4,6) CE(5,7)
    CE(1,2) CE(5,6)
    CE(0,4) CE(1,5) CE(2,6) CE(3,7)
    CE(2,4) CE(3,5)
    CE(1,2) CE(3,4) CE(5,6)
#undef CE
    for (int k=0;k<5;k++){
      float wm = srt[0];
#pragma unroll
      for (int sh=1; sh<64; sh<<=1) wm = fmaxf(wm, __shfl_xor(wm, sh));
      if (l == 0) wtop[w][r][k] = wm;
      unsigned long long bal = __ballot(srt[0] == wm);
      bool mine = (srt[0] == wm) && ((bal & ((1ull<<l) - 1ull)) == 0ull);
      if (mine){   // remove exactly one instance wave-wide
#pragma unroll
        for (int j2=0;j2<7;j2++) srt[j2] = srt[j2+1];
        srt[7] = -INFINITY;
      }
    }
  }
  __syncthreads();

  // ---- cross-wave merge + local window thresholds (one thread per row) ----
  if (tid < 16){
    float m5[5] = {-INFINITY,-INFINITY,-INFINITY,-INFINITY,-INFINITY};
    for (int ww=0; ww<4; ww++)
      for (int k=0;k<5;k++){
        float v = wtop[ww][tid][k];
        float b0 = fminf(m5[0], v); m5[0] = fmaxf(m5[0], v);
        float b1 = fminf(m5[1], b0); m5[1] = fmaxf(m5[1], b0);
        float b2 = fminf(m5[2], b1); m5[2] = fmaxf(m5[2], b1);
        float b3 = fminf(m5[3], b2); m5[3] = fmaxf(m5[3], b2);
        m5[4] = fmaxf(m5[4], b3);
      }
    int R = r0 + tid;
    int b = R & ~1; if (b > 2044) b = 2044;
    float tb = snd_smallest4(diag[tid][b-Lo], diag[tid][b+1-Lo],
                             diag[tid][b+2-Lo], diag[tid][b+3-Lo]);
    float ta = -INFINITY;
    if (b >= 2 && (R - b) <= 1){
      int a0 = b - 2;
      ta = snd_smallest4(diag[tid][a0-Lo], diag[tid][a0+1-Lo],
                         diag[tid][a0+2-Lo], diag[tid][a0+3-Lo]);
    }
    rstat[0][tid] = m5[4];   // thr_g (5th largest, multiplicity-exact)
    rstat[1][tid] = m5[0];   // row max (always survives)
    rstat[2][tid] = tb;
    rstat[3][tid] = ta;
  }
  __syncthreads();

  // ---- phase 3: mask + exp + row sums ----
#pragma unroll
  for (int r=0;r<16;r++){
    int R = r0 + r;
    float tg = rstat[0][r];
    float mx = rstat[1][r];
    float tb = rstat[2][r];
    float ta = rstat[3][r];
    int b = R & ~1; if (b > 2044) b = 2044;
    float rp = 0.f;
#pragma unroll
    for (int m=0;m<8;m++){
      float s = acc[r][m];
      float p = 0.f;
      if (__ballot(s >= tg) != 0ull){   // skip exp work for 64-col groups with no candidate
        int c = cl + (m<<6);
        bool inb = (unsigned)(c - b) < 4u;
        bool ina = (unsigned)(c - (b-2)) < 2u;
        float lt = inb ? tb : (ina ? ta : -INFINITY);
        bool keep = (s >= tg) && (s >= lt);
        p = keep ? expf(s - mx) : 0.f;
      }
      acc[r][m] = p;
      rp += p;
    }
#pragma unroll
    for (int sh=1; sh<64; sh<<=1) rp += __shfl_xor(rp, sh);
    if (l==0) wsum[w][r] = rp;
  }
  __syncthreads();
  if (tid < 16) rstat[0][tid] = wsum[0][tid]+wsum[1][tid]+wsum[2][tid]+wsum[3][tid];
  __syncthreads();

  // ---- phase 3b: write full attn rows (zeros included) + gather survivors ----
  float* attnh = attn + (size_t)head*S_*S_;
#pragma unroll
  for (int r=0;r<16;r++){
    float inv = 1.0f / rstat[0][r];
    size_t rowb = (size_t)(r0 + r) * S_;
#pragma unroll
    for (int m=0;m<8;m++){
      int c = cl + (m<<6);
      float p = acc[r][m];
      float a = p * inv;
      attnh[rowb + c] = a;
      if (p > 0.f){
        int slot = atomicAdd(&scnt[r], 1);
        if (slot < 32){ ssc[r][slot] = c; ssp[r][slot] = a; }
      }
    }
  }
  __syncthreads();

  // ---- phase 4: sparse out = sum attn * v * fi ----
  const float* vh  = V  + (size_t)head*S_*HD_;
  const float* fih = FI + (size_t)head*S_;
  const int bb = head >> 3, hh = head & 7;
#pragma unroll
  for (int rr=0;rr<4;rr++){
    int r = (w<<2) + rr;
    int n = scnt[r]; if (n > 32) n = 32;
    float o = 0.f;
    for (int i=0;i<n;i++){
      int c = ssc[r][i];
      float av = ssp[r][i] * fih[c];
      o = fmaf(av, vh[(size_t)c*HD_ + l], o);
    }
    AO[(((size_t)bb*S_ + (r0+r))*NH_ + hh)*HD_ + l] = o;
  }
}

// =================== proj GEMM: AO(4096x512) @ w_proj(512x512) + b -> out ===================
__global__ __launch_bounds__(256)
void proj_kernel(const float* __restrict__ Ain, const float* __restrict__ wproj,
                 const float* __restrict__ bproj, float* __restrict__ outp)
{
  __shared__ __align__(16) float Al[64][36];
  __shared__ __align__(16) float Bl[32][128];
  const int tid = threadIdx.x;
  const int tx = tid & 15, ty = tid >> 4;
  const int m0 = blockIdx.x * 64, n0 = blockIdx.y * 128;

  float acc[4][8];
#pragma unroll
  for (int i=0;i<4;i++)
#pragma unroll
    for (int j=0;j<8;j++) acc[i][j] = 0.f;

  float4 ra[2], rb[4];
  auto gload = [&](int kc){
#pragma unroll
    for (int p=0;p<2;p++){
      int e = tid + (p<<8);
      int row = e >> 3, kq = (e & 7) << 2;
      ra[p] = *(const float4*)&Ain[(size_t)(m0+row)*512 + kc + kq];
    }
#pragma unroll
    for (int p=0;p<4;p++){
      int e = tid + (p<<8);
      int kr = e >> 5, nq = (e & 31) << 2;
      rb[p] = *(const float4*)&wproj[(size_t)(kc+kr)*512 + n0 + nq];
    }
  };

  gload(0);
  for (int kc=0; kc<512; kc+=32){
    __syncthreads();
#pragma unroll
    for (int p=0;p<2;p++){
      int e = tid + (p<<8);
      int row = e>>3, kq = (e&7)<<2;
      *(float4*)&Al[row][kq] = ra[p];
    }
#pragma unroll
    for (int p=0;p<4;p++){
      int e = tid + (p<<8);
      int kr = e>>5, nq = (e&31)<<2;
      *(float4*)&Bl[kr][nq] = rb[p];
    }
    __syncthreads();
    if (kc < 480) gload(kc+32);
#pragma unroll
    for (int kk=0; kk<32; ++kk){
      float a[4], b[8];
#pragma unroll
      for (int i=0;i<4;i++) a[i] = Al[ty + (i<<4)][kk];
#pragma unroll
      for (int j=0;j<8;j++) b[j] = Bl[kk][tx + (j<<4)];
#pragma unroll
      for (int i=0;i<4;i++)
#pragma unroll
        for (int j=0;j<8;j++) acc[i][j] = fmaf(a[i], b[j], acc[i][j]);
    }
  }

#pragma unroll
  for (int i=0;i<4;i++){
    int m = m0 + ty + (i<<4);
#pragma unroll
    for (int j=0;j<8;j++){
      int n = n0 + tx + (j<<4);
      outp[(size_t)m*512 + n] = acc[i][j] + bproj[n];
    }
  }
}

extern "C" void kernel_launch(void* const* d_in, const int* in_sizes, int n_in,
                              void* d_out, int out_size, void* d_ws, size_t ws_size,
                              hipStream_t stream)
{
  const float* x     = (const float*)d_in[0];
  const float* wqkv  = (const float*)d_in[1];
  const float* bqkv  = (const float*)d_in[2];
  const float* wproj = (const float*)d_in[3];
  const float* bproj = (const float*)d_in[4];

  float* out  = (float*)d_out;               // (2,2048,512) = 2,097,152 floats
  float* attn = out + 2097152;               // (2,8,2048,2048) = 67,108,864 floats

  // workspace: Q, Kt, V, AO (each 2,097,152 floats) + FI (32768) = ~33.7 MB
  float* ws = (float*)d_ws;
  float* Q  = ws;
  float* Kt = Q  + 2097152;
  float* V  = Kt + 2097152;
  float* AO = V  + 2097152;
  float* FI = AO + 2097152;

  qkv_kernel <<<dim3(64,12), 256, 0, stream>>>(x, wqkv, bqkv, Q, Kt, V);
  fi_kernel  <<<8192,        256, 0, stream>>>(Q, FI);
  attn_kernel<<<2048,        256, 0, stream>>>(Q, Kt, V, FI, attn, AO);
  proj_kernel<<<dim3(64,4),  256, 0, stream>>>(AO, wproj, bproj, out);
}

// Round 2
// 751.596 us; speedup vs baseline: 1.0648x; 1.0648x over previous
//
#include <hip/hip_runtime.h>

#define S_  2048
#define HD_ 64
#define NH_ 8

// ---- async global->LDS (16B per lane; LDS dst = wave-uniform base + lane*16) ----
__device__ __forceinline__ void gl_lds16(void* lds, const void* g){
  __builtin_amdgcn_global_load_lds(
      (const __attribute__((address_space(1))) void*)g,
      (__attribute__((address_space(3))) void*)lds, 16, 0, 0);
}

// 2nd smallest of 4 == 3rd largest counting multiplicity (matches top_k[-1] + >= semantics)
__device__ __forceinline__ float snd_smallest4(float a, float b, float c, float d){
  float lo1 = fminf(a,b), hi1 = fmaxf(a,b);
  float lo2 = fminf(c,d), hi2 = fmaxf(c,d);
  return fminf(fmaxf(lo1,lo2), fminf(hi1,hi2));
}

// =================== zero-fill attn (268 MB) at full occupancy ===================
__global__ __launch_bounds__(256)
void fill_kernel(float4* __restrict__ p)
{
  size_t i = (size_t)blockIdx.x*256 + threadIdx.x;   // 4096*256 = 1048576 threads
  const float4 z = {0.f,0.f,0.f,0.f};
#pragma unroll
  for (int k=0;k<16;k++) p[i + (size_t)k*1048576] = z;   // 16 * 16 MB = 268 MB
}

// =================== QKV GEMM: x(4096x512) @ w(512x1536) -> Q/Kt/V ===================
// 128x128 tile, 8x8 per thread, A transposed in LDS -> ds_read_b128 everywhere.
__global__ __launch_bounds__(256)
void qkv_kernel(const float* __restrict__ x, const float* __restrict__ wqkv,
                const float* __restrict__ bqkv,
                float* __restrict__ Q, float* __restrict__ Kt, float* __restrict__ V)
{
  __shared__ __align__(16) float Al[32][132];   // [k][m], pad keeps 16B-aligned rows
  __shared__ __align__(16) float Bl[32][128];   // [k][n]
  const int tid = threadIdx.x;
  const int tx = tid & 15, ty = tid >> 4;
  const int m0 = blockIdx.x * 128, n0 = blockIdx.y * 128;

  float acc[8][8];
#pragma unroll
  for (int i=0;i<8;i++)
#pragma unroll
    for (int j=0;j<8;j++) acc[i][j] = 0.f;

  float4 ra[4], rb[4];
  auto gload = [&](int kc){
#pragma unroll
    for (int p=0;p<4;p++){
      int e = tid + (p<<8);
      int arow = e >> 3, akq = (e & 7) << 2;
      ra[p] = *(const float4*)&x[(size_t)(m0+arow)*512 + kc + akq];
      int krow = e >> 5, bnq = (e & 31) << 2;
      rb[p] = *(const float4*)&wqkv[(size_t)(kc+krow)*1536 + n0 + bnq];
    }
  };

  gload(0);
  for (int kc=0; kc<512; kc+=32){
    __syncthreads();
#pragma unroll
    for (int p=0;p<4;p++){
      int e = tid + (p<<8);
      int arow = e>>3, akq = (e&7)<<2;
      Al[akq+0][arow] = ra[p].x;
      Al[akq+1][arow] = ra[p].y;
      Al[akq+2][arow] = ra[p].z;
      Al[akq+3][arow] = ra[p].w;
      int krow = e>>5, bnq = (e&31)<<2;
      *(float4*)&Bl[krow][bnq] = rb[p];
    }
    __syncthreads();
    if (kc < 480) gload(kc+32);
#pragma unroll
    for (int kk=0; kk<32; ++kk){
      float a[8], b[8];
      *(float4*)&a[0] = *(const float4*)&Al[kk][ty<<2];
      *(float4*)&a[4] = *(const float4*)&Al[kk][64 + (ty<<2)];
      *(float4*)&b[0] = *(const float4*)&Bl[kk][tx<<2];
      *(float4*)&b[4] = *(const float4*)&Bl[kk][64 + (tx<<2)];
#pragma unroll
      for (int i=0;i<8;i++)
#pragma unroll
        for (int j=0;j<8;j++) acc[i][j] = fmaf(a[i], b[j], acc[i][j]);
    }
  }

  // epilogue: each 64-col group is uniformly Q, K or V (n0, cj*64 multiples of 64)
#pragma unroll
  for (int cj=0; cj<2; cj++){
    int nb = n0 + (cj<<6);
    int which = nb >> 9;           // 0:Q 1:K 2:V
    int h = (nb >> 6) & 7;
    float4 bq = *(const float4*)&bqkv[nb + (tx<<2)];
#pragma unroll
    for (int ri=0; ri<2; ri++)
#pragma unroll
      for (int i=0;i<4;i++){
        int m = m0 + (ri<<6) + (ty<<2) + i;
        int bb = m >> 11, s = m & 2047;
        float4 v4;
        v4.x = acc[(ri<<2)+i][(cj<<2)+0] + bq.x;
        v4.y = acc[(ri<<2)+i][(cj<<2)+1] + bq.y;
        v4.z = acc[(ri<<2)+i][(cj<<2)+2] + bq.z;
        v4.w = acc[(ri<<2)+i][(cj<<2)+3] + bq.w;
        if (which == 0){
          *(float4*)&Q[(((size_t)bb*NH_ + h)*S_ + s)*HD_ + (tx<<2)] = v4;
        } else if (which == 2){
          *(float4*)&V[(((size_t)bb*NH_ + h)*S_ + s)*HD_ + (tx<<2)] = v4;
        } else {
          size_t kb = ((size_t)bb*NH_ + h)*HD_;
          Kt[(kb + (tx<<2)+0)*S_ + s] = v4.x;
          Kt[(kb + (tx<<2)+1)*S_ + s] = v4.y;
          Kt[(kb + (tx<<2)+2)*S_ + s] = v4.z;
          Kt[(kb + (tx<<2)+3)*S_ + s] = v4.w;
        }
      }
  }
}

// =================== fi = sigmoid(mean_d q)  (key-position gate) ===================
__global__ __launch_bounds__(256)
void fi_kernel(const float* __restrict__ Q, float* __restrict__ FI)
{
  int row = blockIdx.x*4 + (threadIdx.x >> 6);   // row = bh*S + s, 0..32767
  int l = threadIdx.x & 63;
  float v = Q[(size_t)row*HD_ + l];
#pragma unroll
  for (int sh=1; sh<64; sh<<=1) v += __shfl_xor(v, sh);
  if (l == 0){
    float mean = v * (1.0f/64.0f);
    FI[row] = 1.0f / (1.0f + expf(-mean));
  }
}

// =================== fused attention: scores in regs, topk mask, sparse scatter + attn@v ===================
__global__ __launch_bounds__(256, 2)
void attn_kernel(const float* __restrict__ Q, const float* __restrict__ Kt,
                 const float* __restrict__ V, const float* __restrict__ FI,
                 float* __restrict__ attn, float* __restrict__ AO)
{
  __shared__ __align__(16) float qs[16*64];
  __shared__ __align__(16) float kbuf[2][2*S_];   // 2 d-rows per group, 16 KB each
  __shared__ float diag[16][24];
  __shared__ float wtop[4][16][5];
  __shared__ float wsum[4][16];
  __shared__ float rstat[4][16];   // 0 thr_g -> denom, 1 rowmax, 2 t_b, 3 t_a
  __shared__ int   scnt[16];
  __shared__ int   ssc[16][32];
  __shared__ float ssp[16][32];

  const int tid  = threadIdx.x;
  const int w    = tid >> 6, l = tid & 63;
  const int head = blockIdx.x >> 7;
  const int r0   = (blockIdx.x & 127) << 4;
  const int cl   = (w << 9) + l;     // lane owns cols cl + 64*m, m=0..7

  if (tid < 16) scnt[tid] = 0;

  { // stage q rows, pre-scaled by 1/sqrt(HD)=0.125 (exact pow2)
    const float4* qg = (const float4*)(Q + ((size_t)head*S_ + r0)*HD_);
    float4 q4 = qg[tid];
    q4.x *= 0.125f; q4.y *= 0.125f; q4.z *= 0.125f; q4.w *= 0.125f;
    ((float4*)qs)[tid] = q4;
  }

  const float* ktb = Kt + (size_t)head*HD_*S_;
  auto load_group = [&](int g, int buf){   // 16 KB = Kt[2 d][2048 s], wave-chunked
    const char* src = (const char*)(ktb + (size_t)g*2*S_);
    char* dst = (char*)&kbuf[buf][0];
    int wb = w << 12;
#pragma unroll
    for (int i=0;i<4;i++){
      int off = wb + (i<<10);
      gl_lds16(dst + off, src + off + (l<<4));
    }
  };
  load_group(0, 0);

  float acc[16][8];
#pragma unroll
  for (int r=0;r<16;r++)
#pragma unroll
    for (int m=0;m<8;m++) acc[r][m] = 0.f;

  // ---- phase 1: scores (fp32 FMA, double-buffered K staging; same d-order as R1) ----
  for (int g=0; g<32; ++g){
    __syncthreads();                       // drains vmcnt -> kbuf[g&1] ready, prev buf free
    if (g < 31) load_group(g+1, (g+1)&1);
    const float* kb = &kbuf[g&1][0];
    float kv[2][8];
#pragma unroll
    for (int dd=0;dd<2;dd++)
#pragma unroll
      for (int m=0;m<8;m++)
        kv[dd][m] = kb[dd*S_ + cl + (m<<6)];
#pragma unroll
    for (int r=0;r<16;r++){
      float2 q2 = *(const float2*)&qs[(r<<6) + (g<<1)];
#pragma unroll
      for (int m=0;m<8;m++)
        acc[r][m] = fmaf(q2.y, kv[1][m], fmaf(q2.x, kv[0][m], acc[r][m]));
    }
  }

  // ---- phase 2: diag extract + per-wave top5 (exact multiplicity) ----
  const int Lo = (r0 >= 4) ? (r0 - 4) : 0;
  int dmv  = Lo - cl;
  int m0i  = (dmv > 0) ? ((dmv + 63) >> 6) : 0;
  int didx = cl + (m0i << 6) - Lo;
  bool dvalid = (m0i < 8) && ((unsigned)didx < 24u);

#pragma unroll
  for (int r=0;r<16;r++){
    float dv = acc[r][0];
#pragma unroll
    for (int mm=1;mm<8;mm++) dv = (m0i==mm) ? acc[r][mm] : dv;
    if (dvalid) diag[r][didx] = dv;

    float srt[8];
#pragma unroll
    for (int m=0;m<8;m++) srt[m] = acc[r][m];
#define CE(i,j){ float mx_=fmaxf(srt[i],srt[j]); float mn_=fminf(srt[i],srt[j]); srt[i]=mx_; srt[j]=mn_; }
    CE(0,1) CE(2,3) CE(4,5) CE(6,7)
    CE(0,2) CE(1,3) CE(4,6) CE(5,7)
    CE(1,2) CE(5,6)
    CE(0,4) CE(1,5) CE(2,6) CE(3,7)
    CE(2,4) CE(3,5)
    CE(1,2) CE(3,4) CE(5,6)
#undef CE
    for (int k=0;k<5;k++){
      float wm = srt[0];
#pragma unroll
      for (int sh=1; sh<64; sh<<=1) wm = fmaxf(wm, __shfl_xor(wm, sh));
      if (l == 0) wtop[w][r][k] = wm;
      unsigned long long bal = __ballot(srt[0] == wm);
      bool mine = (srt[0] == wm) && ((bal & ((1ull<<l) - 1ull)) == 0ull);
      if (mine){   // remove exactly one instance wave-wide
#pragma unroll
        for (int j2=0;j2<7;j2++) srt[j2] = srt[j2+1];
        srt[7] = -INFINITY;
      }
    }
  }
  __syncthreads();

  // ---- cross-wave merge + local window thresholds (one thread per row) ----
  if (tid < 16){
    float m5[5] = {-INFINITY,-INFINITY,-INFINITY,-INFINITY,-INFINITY};
    for (int ww=0; ww<4; ww++)
      for (int k=0;k<5;k++){
        float v = wtop[ww][tid][k];
        float b0 = fminf(m5[0], v); m5[0] = fmaxf(m5[0], v);
        float b1 = fminf(m5[1], b0); m5[1] = fmaxf(m5[1], b0);
        float b2 = fminf(m5[2], b1); m5[2] = fmaxf(m5[2], b1);
        float b3 = fminf(m5[3], b2); m5[3] = fmaxf(m5[3], b2);
        m5[4] = fmaxf(m5[4], b3);
      }
    int R = r0 + tid;
    int b = R & ~1; if (b > 2044) b = 2044;
    float tb = snd_smallest4(diag[tid][b-Lo], diag[tid][b+1-Lo],
                             diag[tid][b+2-Lo], diag[tid][b+3-Lo]);
    float ta = -INFINITY;
    if (b >= 2 && (R - b) <= 1){
      int a0 = b - 2;
      ta = snd_smallest4(diag[tid][a0-Lo], diag[tid][a0+1-Lo],
                         diag[tid][a0+2-Lo], diag[tid][a0+3-Lo]);
    }
    rstat[0][tid] = m5[4];   // thr_g (5th largest, multiplicity-exact)
    rstat[1][tid] = m5[0];   // row max (always survives)
    rstat[2][tid] = tb;
    rstat[3][tid] = ta;
  }
  __syncthreads();

  // ---- phase 3: mask + exp + row sums + gather survivors (store p; normalize later) ----
#pragma unroll
  for (int r=0;r<16;r++){
    int R = r0 + r;
    float tg = rstat[0][r];
    float mx = rstat[1][r];
    float tb = rstat[2][r];
    float ta = rstat[3][r];
    int b = R & ~1; if (b > 2044) b = 2044;
    float rp = 0.f;
#pragma unroll
    for (int m=0;m<8;m++){
      float s = acc[r][m];
      if (__ballot(s >= tg) != 0ull){   // skip 64-col groups with no candidate
        int c = cl + (m<<6);
        bool inb = (unsigned)(c - b) < 4u;
        bool ina = (unsigned)(c - (b-2)) < 2u;
        float lt = inb ? tb : (ina ? ta : -INFINITY);
        if ((s >= tg) && (s >= lt)){
          float p = expf(s - mx);
          rp += p;
          int slot = atomicAdd(&scnt[r], 1);
          if (slot < 32){ ssc[r][slot] = c; ssp[r][slot] = p; }
        }
      }
    }
#pragma unroll
    for (int sh=1; sh<64; sh<<=1) rp += __shfl_xor(rp, sh);
    if (l==0) wsum[w][r] = rp;
  }
  __syncthreads();
  if (tid < 16) rstat[0][tid] = wsum[0][tid]+wsum[1][tid]+wsum[2][tid]+wsum[3][tid];
  __syncthreads();

  // ---- phase 3b: scatter normalized nonzeros into (pre-zeroed) attn ----
  float* attnh = attn + (size_t)head*S_*S_;
  {
    int r2 = tid >> 4, l2 = tid & 15;
    float inv = 1.0f / rstat[0][r2];
    size_t rowb = (size_t)(r0 + r2) * S_;
    int n = scnt[r2]; if (n > 32) n = 32;
    for (int s2 = l2; s2 < n; s2 += 16)
      attnh[rowb + ssc[r2][s2]] = ssp[r2][s2] * inv;
  }

  // ---- phase 4: sparse out = sum attn * v * fi ----
  const float* vh  = V  + (size_t)head*S_*HD_;
  const float* fih = FI + (size_t)head*S_;
  const int bb = head >> 3, hh = head & 7;
#pragma unroll
  for (int rr=0;rr<4;rr++){
    int r = (w<<2) + rr;
    float inv = 1.0f / rstat[0][r];
    int n = scnt[r]; if (n > 32) n = 32;
    float o = 0.f;
    for (int i=0;i<n;i++){
      int c = ssc[r][i];
      float av = ssp[r][i] * inv * fih[c];
      o = fmaf(av, vh[(size_t)c*HD_ + l], o);
    }
    AO[(((size_t)bb*S_ + (r0+r))*NH_ + hh)*HD_ + l] = o;
  }
}

// =================== proj GEMM: AO(4096x512) @ w_proj(512x512) + b -> out ===================
// 64x128 tile, 4x8 per thread, grid (64,4)=256 blocks.
__global__ __launch_bounds__(256)
void proj_kernel(const float* __restrict__ Ain, const float* __restrict__ wproj,
                 const float* __restrict__ bproj, float* __restrict__ outp)
{
  __shared__ __align__(16) float Al[32][68];    // [k][m]
  __shared__ __align__(16) float Bl[32][128];   // [k][n]
  const int tid = threadIdx.x;
  const int tx = tid & 15, ty = tid >> 4;
  const int m0 = blockIdx.x * 64, n0 = blockIdx.y * 128;

  float acc[4][8];
#pragma unroll
  for (int i=0;i<4;i++)
#pragma unroll
    for (int j=0;j<8;j++) acc[i][j] = 0.f;

  float4 ra[2], rb[4];
  auto gload = [&](int kc){
#pragma unroll
    for (int p=0;p<2;p++){
      int e = tid + (p<<8);
      int arow = e >> 3, akq = (e & 7) << 2;
      ra[p] = *(const float4*)&Ain[(size_t)(m0+arow)*512 + kc + akq];
    }
#pragma unroll
    for (int p=0;p<4;p++){
      int e = tid + (p<<8);
      int krow = e >> 5, bnq = (e & 31) << 2;
      rb[p] = *(const float4*)&wproj[(size_t)(kc+krow)*512 + n0 + bnq];
    }
  };

  gload(0);
  for (int kc=0; kc<512; kc+=32){
    __syncthreads();
#pragma unroll
    for (int p=0;p<2;p++){
      int e = tid + (p<<8);
      int arow = e>>3, akq = (e&7)<<2;
      Al[akq+0][arow] = ra[p].x;
      Al[akq+1][arow] = ra[p].y;
      Al[akq+2][arow] = ra[p].z;
      Al[akq+3][arow] = ra[p].w;
    }
#pragma unroll
    for (int p=0;p<4;p++){
      int e = tid + (p<<8);
      int krow = e>>5, bnq = (e&31)<<2;
      *(float4*)&Bl[krow][bnq] = rb[p];
    }
    __syncthreads();
    if (kc < 480) gload(kc+32);
#pragma unroll
    for (int kk=0; kk<32; ++kk){
      float a[4], b[8];
      *(float4*)&a[0] = *(const float4*)&Al[kk][ty<<2];
      *(float4*)&b[0] = *(const float4*)&Bl[kk][tx<<2];
      *(float4*)&b[4] = *(const float4*)&Bl[kk][64 + (tx<<2)];
#pragma unroll
      for (int i=0;i<4;i++)
#pragma unroll
        for (int j=0;j<8;j++) acc[i][j] = fmaf(a[i], b[j], acc[i][j]);
    }
  }

#pragma unroll
  for (int cj=0; cj<2; cj++){
    float4 bq = *(const float4*)&bproj[n0 + (cj<<6) + (tx<<2)];
#pragma unroll
    for (int i=0;i<4;i++){
      int m = m0 + (ty<<2) + i;
      float4 v4;
      v4.x = acc[i][(cj<<2)+0] + bq.x;
      v4.y = acc[i][(cj<<2)+1] + bq.y;
      v4.z = acc[i][(cj<<2)+2] + bq.z;
      v4.w = acc[i][(cj<<2)+3] + bq.w;
      *(float4*)&outp[(size_t)m*512 + n0 + (cj<<6) + (tx<<2)] = v4;
    }
  }
}

extern "C" void kernel_launch(void* const* d_in, const int* in_sizes, int n_in,
                              void* d_out, int out_size, void* d_ws, size_t ws_size,
                              hipStream_t stream)
{
  const float* x     = (const float*)d_in[0];
  const float* wqkv  = (const float*)d_in[1];
  const float* bqkv  = (const float*)d_in[2];
  const float* wproj = (const float*)d_in[3];
  const float* bproj = (const float*)d_in[4];

  float* out  = (float*)d_out;               // (2,2048,512) = 2,097,152 floats
  float* attn = out + 2097152;               // (2,8,2048,2048) = 67,108,864 floats

  // workspace: Q, Kt, V, AO (each 2,097,152 floats) + FI (32768) = ~33.7 MB
  float* ws = (float*)d_ws;
  float* Q  = ws;
  float* Kt = Q  + 2097152;
  float* V  = Kt + 2097152;
  float* AO = V  + 2097152;
  float* FI = AO + 2097152;

  fill_kernel<<<4096,        256, 0, stream>>>((float4*)attn);
  qkv_kernel <<<dim3(32,12), 256, 0, stream>>>(x, wqkv, bqkv, Q, Kt, V);
  fi_kernel  <<<8192,        256, 0, stream>>>(Q, FI);
  attn_kernel<<<2048,        256, 0, stream>>>(Q, Kt, V, FI, attn, AO);
  proj_kernel<<<dim3(64,4),  256, 0, stream>>>(AO, wproj, bproj, out);
}

// Round 3
// 675.294 us; speedup vs baseline: 1.1851x; 1.1130x over previous
//
#include <hip/hip_runtime.h>

#define S_  2048
#define HD_ 64
#define NH_ 8

// 2nd smallest of 4 == 3rd largest counting multiplicity (matches top_k[-1] + >= semantics)
__device__ __forceinline__ float snd_smallest4(float a, float b, float c, float d){
  float lo1 = fminf(a,b), hi1 = fmaxf(a,b);
  float lo2 = fminf(c,d), hi2 = fmaxf(c,d);
  return fminf(fmaxf(lo1,lo2), fminf(hi1,hi2));
}

// =================== QKV GEMM: x(4096x512) @ w(512x1536) -> Q/Kt/V ===================
__global__ __launch_bounds__(256)
void qkv_kernel(const float* __restrict__ x, const float* __restrict__ wqkv,
                const float* __restrict__ bqkv,
                float* __restrict__ Q, float* __restrict__ Kt, float* __restrict__ V)
{
  __shared__ __align__(16) float Al[32][132];   // [k][m]
  __shared__ __align__(16) float Bl[32][128];   // [k][n]
  const int tid = threadIdx.x;
  const int tx = tid & 15, ty = tid >> 4;
  const int m0 = blockIdx.x * 128, n0 = blockIdx.y * 128;

  float acc[8][8];
#pragma unroll
  for (int i=0;i<8;i++)
#pragma unroll
    for (int j=0;j<8;j++) acc[i][j] = 0.f;

  float4 ra[4], rb[4];
  auto gload = [&](int kc){
#pragma unroll
    for (int p=0;p<4;p++){
      int e = tid + (p<<8);
      int arow = e >> 3, akq = (e & 7) << 2;
      ra[p] = *(const float4*)&x[(size_t)(m0+arow)*512 + kc + akq];
      int krow = e >> 5, bnq = (e & 31) << 2;
      rb[p] = *(const float4*)&wqkv[(size_t)(kc+krow)*1536 + n0 + bnq];
    }
  };

  gload(0);
  for (int kc=0; kc<512; kc+=32){
    __syncthreads();
#pragma unroll
    for (int p=0;p<4;p++){
      int e = tid + (p<<8);
      int arow = e>>3, akq = (e&7)<<2;
      Al[akq+0][arow] = ra[p].x;
      Al[akq+1][arow] = ra[p].y;
      Al[akq+2][arow] = ra[p].z;
      Al[akq+3][arow] = ra[p].w;
      int krow = e>>5, bnq = (e&31)<<2;
      *(float4*)&Bl[krow][bnq] = rb[p];
    }
    __syncthreads();
    if (kc < 480) gload(kc+32);
#pragma unroll
    for (int kk=0; kk<32; ++kk){
      float a[8], b[8];
      *(float4*)&a[0] = *(const float4*)&Al[kk][ty<<2];
      *(float4*)&a[4] = *(const float4*)&Al[kk][64 + (ty<<2)];
      *(float4*)&b[0] = *(const float4*)&Bl[kk][tx<<2];
      *(float4*)&b[4] = *(const float4*)&Bl[kk][64 + (tx<<2)];
#pragma unroll
      for (int i=0;i<8;i++)
#pragma unroll
        for (int j=0;j<8;j++) acc[i][j] = fmaf(a[i], b[j], acc[i][j]);
    }
  }

#pragma unroll
  for (int cj=0; cj<2; cj++){
    int nb = n0 + (cj<<6);
    int which = nb >> 9;           // 0:Q 1:K 2:V
    int h = (nb >> 6) & 7;
    float4 bq = *(const float4*)&bqkv[nb + (tx<<2)];
#pragma unroll
    for (int ri=0; ri<2; ri++)
#pragma unroll
      for (int i=0;i<4;i++){
        int m = m0 + (ri<<6) + (ty<<2) + i;
        int bb = m >> 11, s = m & 2047;
        float4 v4;
        v4.x = acc[(ri<<2)+i][(cj<<2)+0] + bq.x;
        v4.y = acc[(ri<<2)+i][(cj<<2)+1] + bq.y;
        v4.z = acc[(ri<<2)+i][(cj<<2)+2] + bq.z;
        v4.w = acc[(ri<<2)+i][(cj<<2)+3] + bq.w;
        if (which == 0){
          *(float4*)&Q[(((size_t)bb*NH_ + h)*S_ + s)*HD_ + (tx<<2)] = v4;
        } else if (which == 2){
          *(float4*)&V[(((size_t)bb*NH_ + h)*S_ + s)*HD_ + (tx<<2)] = v4;
        } else {
          size_t kb = ((size_t)bb*NH_ + h)*HD_;
          Kt[(kb + (tx<<2)+0)*S_ + s] = v4.x;
          Kt[(kb + (tx<<2)+1)*S_ + s] = v4.y;
          Kt[(kb + (tx<<2)+2)*S_ + s] = v4.z;
          Kt[(kb + (tx<<2)+3)*S_ + s] = v4.w;
        }
      }
  }
}

// =================== fi = sigmoid(mean_d q) ===================
__global__ __launch_bounds__(256)
void fi_kernel(const float* __restrict__ Q, float* __restrict__ FI)
{
  int row = blockIdx.x*4 + (threadIdx.x >> 6);
  int l = threadIdx.x & 63;
  float v = Q[(size_t)row*HD_ + l];
#pragma unroll
  for (int sh=1; sh<64; sh<<=1) v += __shfl_xor(v, sh);
  if (l == 0){
    float mean = v * (1.0f/64.0f);
    FI[row] = 1.0f / (1.0f + expf(-mean));
  }
}

// =================== fused attention ===================
// 16 rows x 2048 cols per block; lane owns 8 CONSECUTIVE cols c0..c0+7.
// K read directly from L2 (no reuse in-block -> no LDS staging, no barriers in phase 1).
__global__ __launch_bounds__(256, 1)
void attn_kernel(const float* __restrict__ Q, const float* __restrict__ Kt,
                 const float* __restrict__ V, const float* __restrict__ FI,
                 float* __restrict__ attn, float* __restrict__ AO)
{
  __shared__ __align__(16) float qs[16*64];
  __shared__ float diag[16][24];
  __shared__ float wtop[4][16][5];
  __shared__ float wsum[4][16];
  __shared__ float rstat[4][16];   // 0 thr_g -> denom, 1 rowmax, 2 t_b, 3 t_a
  __shared__ int   scnt[16];
  __shared__ int   ssc[16][32];
  __shared__ float ssp[16][32];

  const int tid  = threadIdx.x;
  const int w    = tid >> 6, l = tid & 63;
  const int head = blockIdx.x >> 7;
  const int r0   = (blockIdx.x & 127) << 4;
  const int c0   = (w << 9) + (l << 3);    // lane's 8 consecutive columns

  if (tid < 16) scnt[tid] = 0;

  float* attnh = attn + (size_t)head*S_*S_;

  // ---- zero-fill this block's 16 attn rows (wave w owns rows 4w..4w+3) ----
  {
    const float4 z4 = {0.f,0.f,0.f,0.f};
    float4* zp = (float4*)(attnh + (size_t)(r0 + (w<<2))*S_) + l;
#pragma unroll
    for (int rr=0;rr<4;rr++)
#pragma unroll
      for (int i=0;i<8;i++)
        zp[rr*512 + i*64] = z4;
  }

  { // stage q rows, pre-scaled by 1/sqrt(HD)=0.125 (exact pow2)
    const float4* qg = (const float4*)(Q + ((size_t)head*S_ + r0)*HD_);
    float4 q4 = qg[tid];
    q4.x *= 0.125f; q4.y *= 0.125f; q4.z *= 0.125f; q4.w *= 0.125f;
    ((float4*)qs)[tid] = q4;
  }
  __syncthreads();

  const float* kcol = Kt + (size_t)head*HD_*S_ + c0;

  float acc[16][8];
#pragma unroll
  for (int r=0;r<16;r++)
#pragma unroll
    for (int m=0;m<8;m++) acc[r][m] = 0.f;

  // ---- phase 1: scores, fp32 FMA, d ascending (same summation order as R2) ----
  float4 ka0, kb0, ka1, kb1, na0, nb0, na1, nb1;
  ka0 = *(const float4*)(kcol + 0*S_);
  kb0 = *(const float4*)(kcol + 0*S_ + 4);
  ka1 = *(const float4*)(kcol + 1*S_);
  kb1 = *(const float4*)(kcol + 1*S_ + 4);
  for (int dp=0; dp<32; ++dp){
    if (dp < 31){
      const float* base = kcol + (size_t)(2*dp+2)*S_;
      na0 = *(const float4*)(base);
      nb0 = *(const float4*)(base + 4);
      na1 = *(const float4*)(base + S_);
      nb1 = *(const float4*)(base + S_ + 4);
    }
#pragma unroll
    for (int r=0;r<16;r++){
      float2 q2 = *(const float2*)&qs[(r<<6) + (dp<<1)];
      acc[r][0] = fmaf(q2.y, ka1.x, fmaf(q2.x, ka0.x, acc[r][0]));
      acc[r][1] = fmaf(q2.y, ka1.y, fmaf(q2.x, ka0.y, acc[r][1]));
      acc[r][2] = fmaf(q2.y, ka1.z, fmaf(q2.x, ka0.z, acc[r][2]));
      acc[r][3] = fmaf(q2.y, ka1.w, fmaf(q2.x, ka0.w, acc[r][3]));
      acc[r][4] = fmaf(q2.y, kb1.x, fmaf(q2.x, kb0.x, acc[r][4]));
      acc[r][5] = fmaf(q2.y, kb1.y, fmaf(q2.x, kb0.y, acc[r][5]));
      acc[r][6] = fmaf(q2.y, kb1.z, fmaf(q2.x, kb0.z, acc[r][6]));
      acc[r][7] = fmaf(q2.y, kb1.w, fmaf(q2.x, kb0.w, acc[r][7]));
    }
    ka0 = na0; kb0 = nb0; ka1 = na1; kb1 = nb1;
  }

  // ---- diag extract (scores[r][c] for c in [Lo, Lo+24)) ----
  const int Lo = (r0 >= 4) ? (r0 - 4) : 0;
  if (c0 + 8 > Lo && c0 < Lo + 24){
#pragma unroll
    for (int r=0;r<16;r++)
#pragma unroll
      for (int j=0;j<8;j++){
        int di = c0 + j - Lo;
        if ((unsigned)di < 24u) diag[r][di] = acc[r][j];
      }
  }

  // ---- phase 2: per-wave top-5 via sort8 + bitonic list-merge butterfly ----
  float lmax[16];
#define CE(x,y){ float mx_=fmaxf(x,y); float mn_=fminf(x,y); x=mx_; y=mn_; }
#pragma unroll
  for (int r=0;r<16;r++){
    float s0=acc[r][0], s1=acc[r][1], s2=acc[r][2], s3=acc[r][3];
    float s4=acc[r][4], s5=acc[r][5], s6=acc[r][6], s7=acc[r][7];
    // Batcher odd-even merge sort 8, descending (19 CE)
    CE(s0,s1) CE(s2,s3) CE(s4,s5) CE(s6,s7)
    CE(s0,s2) CE(s1,s3) CE(s4,s6) CE(s5,s7)
    CE(s1,s2) CE(s5,s6)
    CE(s0,s4) CE(s1,s5) CE(s2,s6) CE(s3,s7)
    CE(s2,s4) CE(s3,s5)
    CE(s1,s2) CE(s3,s4) CE(s5,s6)
    lmax[r] = s0;
    float a0=s0, a1=s1, a2=s2, a3=s3, a4=s4;
#pragma unroll
    for (int st=1; st<64; st<<=1){
      float b0 = __shfl_xor(a4, st);
      float b1 = __shfl_xor(a3, st);
      float b2 = __shfl_xor(a2, st);
      float b3 = __shfl_xor(a1, st);
      float b4 = __shfl_xor(a0, st);
      float t0 = fmaxf(a0,b0), t1 = fmaxf(a1,b1), t2 = fmaxf(a2,b2);
      float t3 = fmaxf(a3,b3), t4 = fmaxf(a4,b4);
      // sort5 desc (9 CE)
      CE(t0,t1) CE(t3,t4) CE(t2,t4) CE(t2,t3) CE(t1,t4)
      CE(t0,t3) CE(t0,t2) CE(t1,t3) CE(t1,t2)
      a0=t0; a1=t1; a2=t2; a3=t3; a4=t4;
    }
    if (l == 0){
      wtop[w][r][0]=a0; wtop[w][r][1]=a1; wtop[w][r][2]=a2;
      wtop[w][r][3]=a3; wtop[w][r][4]=a4;
    }
  }
#undef CE
  __syncthreads();

  // ---- cross-wave merge + local window thresholds (one thread per row) ----
  if (tid < 16){
    float m5[5] = {-INFINITY,-INFINITY,-INFINITY,-INFINITY,-INFINITY};
    for (int ww=0; ww<4; ww++)
      for (int k=0;k<5;k++){
        float v = wtop[ww][tid][k];
        float b0 = fminf(m5[0], v); m5[0] = fmaxf(m5[0], v);
        float b1 = fminf(m5[1], b0); m5[1] = fmaxf(m5[1], b0);
        float b2 = fminf(m5[2], b1); m5[2] = fmaxf(m5[2], b1);
        float b3 = fminf(m5[3], b2); m5[3] = fmaxf(m5[3], b2);
        m5[4] = fmaxf(m5[4], b3);
      }
    int R = r0 + tid;
    int b = R & ~1; if (b > 2044) b = 2044;
    float tb = snd_smallest4(diag[tid][b-Lo], diag[tid][b+1-Lo],
                             diag[tid][b+2-Lo], diag[tid][b+3-Lo]);
    float ta = -INFINITY;
    if (b >= 2 && (R - b) <= 1){
      int a0 = b - 2;
      ta = snd_smallest4(diag[tid][a0-Lo], diag[tid][a0+1-Lo],
                         diag[tid][a0+2-Lo], diag[tid][a0+3-Lo]);
    }
    rstat[0][tid] = m5[4];   // thr_g (5th largest, multiplicity-exact)
    rstat[1][tid] = m5[0];   // row max
    rstat[2][tid] = tb;
    rstat[3][tid] = ta;
  }
  __syncthreads();

  // ---- phase 3: mask + exp + row sums + gather survivors ----
#pragma unroll
  for (int r=0;r<16;r++){
    int R = r0 + r;
    float tg = rstat[0][r];
    float mx = rstat[1][r];
    float tb = rstat[2][r];
    float ta = rstat[3][r];
    int b = R & ~1; if (b > 2044) b = 2044;
    float rp = 0.f;
    if (lmax[r] >= tg){   // only lanes holding a candidate enter
#pragma unroll
      for (int j=0;j<8;j++){
        float s = acc[r][j];
        int c = c0 + j;
        bool inb = (unsigned)(c - b) < 4u;
        bool ina = (unsigned)(c - (b-2)) < 2u;
        float lt = inb ? tb : (ina ? ta : -INFINITY);
        if ((s >= tg) && (s >= lt)){
          float p = expf(s - mx);
          rp += p;
          int slot = atomicAdd(&scnt[r], 1);
          if (slot < 32){ ssc[r][slot] = c; ssp[r][slot] = p; }
        }
      }
    }
#pragma unroll
    for (int sh=1; sh<64; sh<<=1) rp += __shfl_xor(rp, sh);
    if (l==0) wsum[w][r] = rp;
  }
  __syncthreads();
  if (tid < 16) rstat[0][tid] = wsum[0][tid]+wsum[1][tid]+wsum[2][tid]+wsum[3][tid];
  __syncthreads();   // also guarantees the zero-fill stores above are complete

  // ---- phase 3b: scatter normalized nonzeros (same wave that zero-filled the row) ----
  {
#pragma unroll
    for (int rr=0;rr<4;rr++){
      int r = (w<<2) + rr;
      float inv = 1.0f / rstat[0][r];
      size_t rowb = (size_t)(r0 + r) * S_;
      int n = scnt[r]; if (n > 32) n = 32;
      for (int s2 = l; s2 < n; s2 += 64)
        attnh[rowb + ssc[r][s2]] = ssp[r][s2] * inv;
    }
  }

  // ---- phase 4: sparse out = sum attn * v * fi ----
  const float* vh  = V  + (size_t)head*S_*HD_;
  const float* fih = FI + (size_t)head*S_;
  const int bb = head >> 3, hh = head & 7;
#pragma unroll
  for (int rr=0;rr<4;rr++){
    int r = (w<<2) + rr;
    float inv = 1.0f / rstat[0][r];
    int n = scnt[r]; if (n > 32) n = 32;
    float o = 0.f;
    for (int i=0;i<n;i++){
      int c = ssc[r][i];
      float av = ssp[r][i] * inv * fih[c];
      o = fmaf(av, vh[(size_t)c*HD_ + l], o);
    }
    AO[(((size_t)bb*S_ + (r0+r))*NH_ + hh)*HD_ + l] = o;
  }
}

// =================== proj GEMM: AO(4096x512) @ w_proj(512x512) + b -> out ===================
__global__ __launch_bounds__(256)
void proj_kernel(const float* __restrict__ Ain, const float* __restrict__ wproj,
                 const float* __restrict__ bproj, float* __restrict__ outp)
{
  __shared__ __align__(16) float Al[32][68];
  __shared__ __align__(16) float Bl[32][128];
  const int tid = threadIdx.x;
  const int tx = tid & 15, ty = tid >> 4;
  const int m0 = blockIdx.x * 64, n0 = blockIdx.y * 128;

  float acc[4][8];
#pragma unroll
  for (int i=0;i<4;i++)
#pragma unroll
    for (int j=0;j<8;j++) acc[i][j] = 0.f;

  float4 ra[2], rb[4];
  auto gload = [&](int kc){
#pragma unroll
    for (int p=0;p<2;p++){
      int e = tid + (p<<8);
      int arow = e >> 3, akq = (e & 7) << 2;
      ra[p] = *(const float4*)&Ain[(size_t)(m0+arow)*512 + kc + akq];
    }
#pragma unroll
    for (int p=0;p<4;p++){
      int e = tid + (p<<8);
      int krow = e >> 5, bnq = (e & 31) << 2;
      rb[p] = *(const float4*)&wproj[(size_t)(kc+krow)*512 + n0 + bnq];
    }
  };

  gload(0);
  for (int kc=0; kc<512; kc+=32){
    __syncthreads();
#pragma unroll
    for (int p=0;p<2;p++){
      int e = tid + (p<<8);
      int arow = e>>3, akq = (e&7)<<2;
      Al[akq+0][arow] = ra[p].x;
      Al[akq+1][arow] = ra[p].y;
      Al[akq+2][arow] = ra[p].z;
      Al[akq+3][arow] = ra[p].w;
    }
#pragma unroll
    for (int p=0;p<4;p++){
      int e = tid + (p<<8);
      int krow = e>>5, bnq = (e&31)<<2;
      *(float4*)&Bl[krow][bnq] = rb[p];
    }
    __syncthreads();
    if (kc < 480) gload(kc+32);
#pragma unroll
    for (int kk=0; kk<32; ++kk){
      float a[4], b[8];
      *(float4*)&a[0] = *(const float4*)&Al[kk][ty<<2];
      *(float4*)&b[0] = *(const float4*)&Bl[kk][tx<<2];
      *(float4*)&b[4] = *(const float4*)&Bl[kk][64 + (tx<<2)];
#pragma unroll
      for (int i=0;i<4;i++)
#pragma unroll
        for (int j=0;j<8;j++) acc[i][j] = fmaf(a[i], b[j], acc[i][j]);
    }
  }

#pragma unroll
  for (int cj=0; cj<2; cj++){
    float4 bq = *(const float4*)&bproj[n0 + (cj<<6) + (tx<<2)];
#pragma unroll
    for (int i=0;i<4;i++){
      int m = m0 + (ty<<2) + i;
      float4 v4;
      v4.x = acc[i][(cj<<2)+0] + bq.x;
      v4.y = acc[i][(cj<<2)+1] + bq.y;
      v4.z = acc[i][(cj<<2)+2] + bq.z;
      v4.w = acc[i][(cj<<2)+3] + bq.w;
      *(float4*)&outp[(size_t)m*512 + n0 + (cj<<6) + (tx<<2)] = v4;
    }
  }
}

extern "C" void kernel_launch(void* const* d_in, const int* in_sizes, int n_in,
                              void* d_out, int out_size, void* d_ws, size_t ws_size,
                              hipStream_t stream)
{
  const float* x     = (const float*)d_in[0];
  const float* wqkv  = (const float*)d_in[1];
  const float* bqkv  = (const float*)d_in[2];
  const float* wproj = (const float*)d_in[3];
  const float* bproj = (const float*)d_in[4];

  float* out  = (float*)d_out;               // (2,2048,512)
  float* attn = out + 2097152;               // (2,8,2048,2048)

  float* ws = (float*)d_ws;
  float* Q  = ws;
  float* Kt = Q  + 2097152;
  float* V  = Kt + 2097152;
  float* AO = V  + 2097152;
  float* FI = AO + 2097152;

  qkv_kernel <<<dim3(32,12), 256, 0, stream>>>(x, wqkv, bqkv, Q, Kt, V);
  fi_kernel  <<<8192,        256, 0, stream>>>(Q, FI);
  attn_kernel<<<2048,        256, 0, stream>>>(Q, Kt, V, FI, attn, AO);
  proj_kernel<<<dim3(64,4),  256, 0, stream>>>(AO, wproj, bproj, out);
}

// Round 7
// 609.717 us; speedup vs baseline: 1.3126x; 1.1076x over previous
//
#include <hip/hip_runtime.h>

#define S_  2048
#define HD_ 64
#define NH_ 8
#define MARGIN 4e-3f

typedef _Float16 half8 __attribute__((ext_vector_type(8)));
typedef _Float16 half4v __attribute__((ext_vector_type(4)));
typedef float    f32x4 __attribute__((ext_vector_type(4)));

// 2nd smallest of 4 == 3rd largest counting multiplicity (matches top_k[-1] + >= semantics)
__device__ __forceinline__ float snd_smallest4(float a, float b, float c, float d){
  float lo1 = fminf(a,b), hi1 = fmaxf(a,b);
  float lo2 = fminf(c,d), hi2 = fmaxf(c,d);
  return fminf(fmaxf(lo1,lo2), fminf(hi1,hi2));
}

// exact fp32 dot, R3-validated summation order (d ascending, paired FMA chain)
// qrow is pre-scaled by 0.125 -> result = q.k/8
__device__ __forceinline__ float dot64(const float* __restrict__ qrow,
                                       const float* __restrict__ kcol){
  float acc = 0.f;
#pragma unroll
  for (int dp=0; dp<32; ++dp){
    float2 k2 = *(const float2*)(kcol + 2*dp);
    acc = fmaf(qrow[2*dp+1], k2.y, fmaf(qrow[2*dp], k2.x, acc));
  }
  return acc;
}

// =================== QKV GEMM: x(4096x512) @ w(512x1536) -> Qf/Kf/Khi/V/FI ===================
__global__ __launch_bounds__(256, 2)
void qkv_kernel(const float* __restrict__ x, const float* __restrict__ wqkv,
                const float* __restrict__ bqkv,
                float* __restrict__ Qf, float* __restrict__ Kf,
                _Float16* __restrict__ Khi,
                float* __restrict__ V, float* __restrict__ FI)
{
  __shared__ __align__(16) float Al[32][132];   // [k][m]
  __shared__ __align__(16) float Bl[32][128];   // [k][n]
  const int tid = threadIdx.x;
  const int tx = tid & 15, ty = tid >> 4;
  const int m0 = blockIdx.x * 128, n0 = blockIdx.y * 128;

  float acc[8][8];
#pragma unroll
  for (int i=0;i<8;i++)
#pragma unroll
    for (int j=0;j<8;j++) acc[i][j] = 0.f;

  float4 ra[4], rb[4];
  auto gload = [&](int kc){
#pragma unroll
    for (int p=0;p<4;p++){
      int e = tid + (p<<8);
      int arow = e >> 3, akq = (e & 7) << 2;
      ra[p] = *(const float4*)&x[(size_t)(m0+arow)*512 + kc + akq];
      int krow = e >> 5, bnq = (e & 31) << 2;
      rb[p] = *(const float4*)&wqkv[(size_t)(kc+krow)*1536 + n0 + bnq];
    }
  };

  gload(0);
  for (int kc=0; kc<512; kc+=32){
    __syncthreads();
#pragma unroll
    for (int p=0;p<4;p++){
      int e = tid + (p<<8);
      int arow = e>>3, akq = (e&7)<<2;
      Al[akq+0][arow] = ra[p].x;
      Al[akq+1][arow] = ra[p].y;
      Al[akq+2][arow] = ra[p].z;
      Al[akq+3][arow] = ra[p].w;
      int krow = e>>5, bnq = (e&31)<<2;
      *(float4*)&Bl[krow][bnq] = rb[p];
    }
    __syncthreads();
    if (kc < 480) gload(kc+32);
#pragma unroll
    for (int kk=0; kk<32; ++kk){
      float a[8], b[8];
      *(float4*)&a[0] = *(const float4*)&Al[kk][ty<<2];
      *(float4*)&a[4] = *(const float4*)&Al[kk][64 + (ty<<2)];
      *(float4*)&b[0] = *(const float4*)&Bl[kk][tx<<2];
      *(float4*)&b[4] = *(const float4*)&Bl[kk][64 + (tx<<2)];
#pragma unroll
      for (int i=0;i<8;i++)
#pragma unroll
        for (int j=0;j<8;j++) acc[i][j] = fmaf(a[i], b[j], acc[i][j]);
    }
  }

  // epilogue: each 64-col group is uniformly one head of Q, K or V (all stores coalesced)
#pragma unroll
  for (int cj=0; cj<2; cj++){
    int nb = n0 + (cj<<6);
    int which = nb >> 9;           // 0:Q 1:K 2:V
    int h = (nb >> 6) & 7;
    float4 bq = *(const float4*)&bqkv[nb + (tx<<2)];
#pragma unroll
    for (int ri=0; ri<2; ri++)
#pragma unroll
      for (int i=0;i<4;i++){
        int m = m0 + (ri<<6) + (ty<<2) + i;
        int bb = m >> 11, s = m & 2047;
        float4 v4;
        v4.x = acc[(ri<<2)+i][(cj<<2)+0] + bq.x;
        v4.y = acc[(ri<<2)+i][(cj<<2)+1] + bq.y;
        v4.z = acc[(ri<<2)+i][(cj<<2)+2] + bq.z;
        v4.w = acc[(ri<<2)+i][(cj<<2)+3] + bq.w;
        size_t base = (((size_t)bb*NH_ + h)*S_ + s)*HD_ + (tx<<2);
        if (which == 2){
          *(float4*)&V[base] = v4;
        } else if (which == 0){
          *(float4*)&Qf[base] = v4;
          // fi = sigmoid(mean_d q) — reduce over the 16 tx lanes (full d range of row m)
          float fs = v4.x + v4.y + v4.z + v4.w;
#pragma unroll
          for (int st=1; st<16; st<<=1) fs += __shfl_xor(fs, st);
          if (tx == 0)
            FI[((size_t)bb*NH_ + h)*S_ + s] = 1.0f / (1.0f + expf(-fs * (1.0f/64.0f)));
        } else {
          *(float4*)&Kf[base] = v4;
          half4v hv;
          hv[0] = (_Float16)(v4.x * 16.0f);
          hv[1] = (_Float16)(v4.y * 16.0f);
          hv[2] = (_Float16)(v4.z * 16.0f);
          hv[3] = (_Float16)(v4.w * 16.0f);
          *(half4v*)&Khi[base] = hv;
        }
      }
  }
}

// =================== fused attention: MFMA prune -> exact fp32 selection -> scatter + sparse PV ===================
#define CE(x,y){ float mx_=fmaxf(x,y), mn_=fminf(x,y); x=mx_; y=mn_; }
#define SORT8(s0,s1,s2,s3,s4,s5,s6,s7) \
    CE(s0,s1) CE(s2,s3) CE(s4,s5) CE(s6,s7) \
    CE(s0,s2) CE(s1,s3) CE(s4,s6) CE(s5,s7) \
    CE(s1,s2) CE(s5,s6) \
    CE(s0,s4) CE(s1,s5) CE(s2,s6) CE(s3,s7) \
    CE(s2,s4) CE(s3,s5) \
    CE(s1,s2) CE(s3,s4) CE(s5,s6)
#define SORT5(t0,t1,t2,t3,t4) \
    CE(t0,t1) CE(t3,t4) CE(t2,t4) CE(t2,t3) CE(t1,t4) \
    CE(t0,t3) CE(t0,t2) CE(t1,t3) CE(t1,t2)
#define MERGE5(a0,a1,a2,a3,a4,b0,b1,b2,b3,b4) { \
    a0 = fmaxf(a0,b4); a1 = fmaxf(a1,b3); a2 = fmaxf(a2,b2); \
    a3 = fmaxf(a3,b1); a4 = fmaxf(a4,b0); \
    SORT5(a0,a1,a2,a3,a4) }

__global__ __launch_bounds__(256, 2)
void attn_kernel(const float* __restrict__ Qf, const float* __restrict__ Kf,
                 const _Float16* __restrict__ Khi,
                 const float* __restrict__ V, const float* __restrict__ FI,
                 float* __restrict__ attn, float* __restrict__ AO)
{
  __shared__ __align__(16) float qsl[16*64];   // q rows, pre-scaled 0.125
  __shared__ float diag[16][24];               // EXACT window scores
  __shared__ float wtop[4][16][5];             // approx per-wave top5
  __shared__ float tgA[16];                    // approx thr_g
  __shared__ int   ccnt[16];
  __shared__ int   ccol[16][32];
  __shared__ float cex[16][32];

  const int tid  = threadIdx.x;
  const int w    = tid >> 6, l = tid & 63;
  const int quad = l >> 4, ln = l & 15;
  const int head = blockIdx.x >> 7;
  const int r0   = (blockIdx.x & 127) << 4;
  const int cb   = w << 9;               // wave's 512-col window

  if (tid < 16) ccnt[tid] = 0;

  float* attnh = attn + (size_t)head*S_*S_;

  // ---- zero-fill this block's 16 attn rows (wave w owns rows 4w..4w+3) ----
  {
    const float4 z4 = {0.f,0.f,0.f,0.f};
    float4* zp = (float4*)(attnh + (size_t)(r0 + (w<<2))*S_) + l;
#pragma unroll
    for (int rr=0;rr<4;rr++)
#pragma unroll
      for (int i=0;i<8;i++)
        zp[rr*512 + i*64] = z4;
  }

  // ---- stage q rows (scaled 0.125, exact pow2) ----
  {
    const float4* qg = (const float4*)(Qf + ((size_t)head*S_ + r0)*HD_);
    float4 q4 = qg[tid];
    q4.x *= 0.125f; q4.y *= 0.125f; q4.z *= 0.125f; q4.w *= 0.125f;
    ((float4*)qsl)[tid] = q4;
  }
  __syncthreads();

  // ---- A-fragments (hi plane): A[m=ln][k=quad*8+j (+32)] from LDS q (x128 = 16q) ----
  half8 a_h0, a_h1;
#pragma unroll
  for (int j=0;j<8;j++){
    a_h0[j] = (_Float16)(qsl[ln*HD_ + quad*8 + j] * 128.0f);
    a_h1[j] = (_Float16)(qsl[ln*HD_ + quad*8 + j + 32] * 128.0f);
  }

  const _Float16* kh = Khi + (size_t)head*S_*HD_;
  const float*    kf = Kf  + (size_t)head*S_*HD_;

  // ---- phase 1: APPROX scores via hi-hi MFMA. sc[4t+g] ~= S[quad*4+g][cb+16t+ln] ----
  float sc[128];
#pragma unroll
  for (int t=0; t<32; ++t){
    size_t boff = (size_t)(cb + (t<<4) + ln)*HD_ + quad*8;
    half8 bh0 = *(const half8*)(kh + boff);
    half8 bh1 = *(const half8*)(kh + boff + 32);
    f32x4 a4 = {0.f,0.f,0.f,0.f};
    a4 = __builtin_amdgcn_mfma_f32_16x16x32_f16(a_h0, bh0, a4, 0,0,0);
    a4 = __builtin_amdgcn_mfma_f32_16x16x32_f16(a_h1, bh1, a4, 0,0,0);
#pragma unroll
    for (int g=0; g<4; ++g)
      sc[(t<<2)+g] = a4[g] * 0x1p-11f;    // 256*qk -> qk/8
  }

  // ---- phase 2: approx per-row top5 (sort8 + bitonic merges + 16-lane butterfly) ----
  float lmaxA[4];
#pragma unroll
  for (int rr=0; rr<4; ++rr){
    float a0,a1,a2,a3,a4;
    {
      float s0=sc[rr],    s1=sc[4+rr],  s2=sc[8+rr],  s3=sc[12+rr];
      float s4=sc[16+rr], s5=sc[20+rr], s6=sc[24+rr], s7=sc[28+rr];
      SORT8(s0,s1,s2,s3,s4,s5,s6,s7)
      a0=s0; a1=s1; a2=s2; a3=s3; a4=s4;
    }
#pragma unroll
    for (int gofs=32; gofs<128; gofs+=32){
      float s0=sc[gofs+rr],    s1=sc[gofs+4+rr],  s2=sc[gofs+8+rr],  s3=sc[gofs+12+rr];
      float s4=sc[gofs+16+rr], s5=sc[gofs+20+rr], s6=sc[gofs+24+rr], s7=sc[gofs+28+rr];
      SORT8(s0,s1,s2,s3,s4,s5,s6,s7)
      MERGE5(a0,a1,a2,a3,a4, s0,s1,s2,s3,s4)
    }
    lmaxA[rr] = a0;
#pragma unroll
    for (int st=1; st<16; st<<=1){
      float b0 = __shfl_xor(a4, st);
      float b1 = __shfl_xor(a3, st);
      float b2 = __shfl_xor(a2, st);
      float b3 = __shfl_xor(a1, st);
      float b4 = __shfl_xor(a0, st);
      MERGE5(a0,a1,a2,a3,a4, b4,b3,b2,b1,b0)
    }
    if (ln == 0){
      int row = (quad<<2) + rr;
      wtop[w][row][0]=a0; wtop[w][row][1]=a1; wtop[w][row][2]=a2;
      wtop[w][row][3]=a3; wtop[w][row][4]=a4;
    }
  }
  __syncthreads();

  if (tid < 16){
    float m5[5] = {-INFINITY,-INFINITY,-INFINITY,-INFINITY,-INFINITY};
    for (int ww=0; ww<4; ww++)
      for (int k=0;k<5;k++){
        float v = wtop[ww][tid][k];
        float b0 = fminf(m5[0], v); m5[0] = fmaxf(m5[0], v);
        float b1 = fminf(m5[1], b0); m5[1] = fmaxf(m5[1], b0);
        float b2 = fminf(m5[2], b1); m5[2] = fmaxf(m5[2], b1);
        float b3 = fminf(m5[3], b2); m5[3] = fmaxf(m5[3], b2);
        m5[4] = fmaxf(m5[4], b3);
      }
    tgA[tid] = m5[4];
  }
  __syncthreads();

  // ---- phase 3a: candidate gather (approx >= tgA - MARGIN  =>  superset of true top5) ----
#pragma unroll
  for (int rr=0; rr<4; ++rr){
    int row = (quad<<2) + rr;
    float thr = tgA[row] - MARGIN;
    if (lmaxA[rr] >= thr){
#pragma unroll
      for (int t=0; t<32; ++t){
        if (sc[(t<<2)+rr] >= thr){
          int c = cb + (t<<4) + ln;
          int slot = atomicAdd(&ccnt[row], 1);
          if (slot < 32) ccol[row][slot] = c;
        }
      }
    }
  }

  // ---- phase 3b: EXACT diag (window cols [Lo, Lo+24)) via scalar fp32 dots ----
  const int Lo = (r0 >= 4) ? (r0 - 4) : 0;
  {
    int row = tid >> 4, j = tid & 15;
    int c0 = Lo + j;
    if (c0 < S_) diag[row][j] = dot64(qsl + row*HD_, kf + (size_t)c0*HD_);
    if (j < 8){
      int c1 = Lo + 16 + j;
      if (c1 < S_) diag[row][16+j] = dot64(qsl + row*HD_, kf + (size_t)c1*HD_);
    }
  }
  __syncthreads();

  // ---- phase 4: EXACT rescore of candidates ----
  {
    int row = tid >> 4, j = tid & 15;
    int n = ccnt[row]; if (n > 32) n = 32;
    if (j < n)      cex[row][j]    = dot64(qsl + row*HD_, kf + (size_t)ccol[row][j]*HD_);
    if (j + 16 < n) cex[row][j+16] = dot64(qsl + row*HD_, kf + (size_t)ccol[row][j+16]*HD_);
  }
  __syncthreads();

  // ---- phase 5: exact selection + softmax (serial per row; all values exact fp32) ----
  if (tid < 16){
    int n = ccnt[tid]; if (n > 32) n = 32;
    float m5[5] = {-INFINITY,-INFINITY,-INFINITY,-INFINITY,-INFINITY};
    for (int i=0;i<n;i++){
      float v = cex[tid][i];
      float b0 = fminf(m5[0], v); m5[0] = fmaxf(m5[0], v);
      float b1 = fminf(m5[1], b0); m5[1] = fmaxf(m5[1], b0);
      float b2 = fminf(m5[2], b1); m5[2] = fmaxf(m5[2], b1);
      float b3 = fminf(m5[3], b2); m5[3] = fmaxf(m5[3], b2);
      m5[4] = fmaxf(m5[4], b3);
    }
    float tg = m5[4], mx = m5[0];
    int R = r0 + tid;
    int b = R & ~1; if (b > 2044) b = 2044;
    float tb = snd_smallest4(diag[tid][b-Lo], diag[tid][b+1-Lo],
                             diag[tid][b+2-Lo], diag[tid][b+3-Lo]);
    float ta = -INFINITY;
    if (b >= 2 && (R - b) <= 1){
      int a0i = b - 2;
      ta = snd_smallest4(diag[tid][a0i-Lo], diag[tid][a0i+1-Lo],
                         diag[tid][a0i+2-Lo], diag[tid][a0i+3-Lo]);
    }
    float Z = 0.f; int k = 0;
    for (int i=0;i<n;i++){
      float s = cex[tid][i]; int c = ccol[tid][i];
      bool inb = (unsigned)(c - b) < 4u;
      bool ina = (unsigned)(c - (b-2)) < 2u;
      float lt = inb ? tb : (ina ? ta : -INFINITY);
      if (s >= tg && s >= lt){
        float p = expf(s - mx);
        Z += p;
        ccol[tid][k] = c; cex[tid][k] = p; k++;
      }
    }
    float inv = 1.0f / Z;
    for (int i=0;i<k;i++) cex[tid][i] *= inv;   // normalized attn weights
    ccnt[tid] = k;
  }
  __syncthreads();

  // ---- phase 6: scatter normalized nonzeros (wave w owns rows 4w..4w+3) ----
#pragma unroll
  for (int rr=0;rr<4;rr++){
    int r = (w<<2) + rr;
    size_t rowb = (size_t)(r0 + r) * S_;
    int n = ccnt[r];
    for (int s2 = l; s2 < n; s2 += 64)
      attnh[rowb + ccol[r][s2]] = cex[r][s2];
  }

  // ---- phase 7: sparse out = sum attn * v * fi ----
  const float* vh  = V  + (size_t)head*S_*HD_;
  const float* fih = FI + (size_t)head*S_;
  const int bb = head >> 3, hh = head & 7;
#pragma unroll
  for (int rr=0;rr<4;rr++){
    int r = (w<<2) + rr;
    int n = ccnt[r];
    float o = 0.f;
    for (int i=0;i<n;i++){
      int c = ccol[r][i];
      float av = cex[r][i] * fih[c];
      o = fmaf(av, vh[(size_t)c*HD_ + l], o);
    }
    AO[(((size_t)bb*S_ + (r0+r))*NH_ + hh)*HD_ + l] = o;
  }
}
#undef CE
#undef SORT8
#undef SORT5
#undef MERGE5

// =================== proj GEMM: AO(4096x512) @ w_proj(512x512) + b -> out ===================
__global__ __launch_bounds__(256)
void proj_kernel(const float* __restrict__ Ain, const float* __restrict__ wproj,
                 const float* __restrict__ bproj, float* __restrict__ outp)
{
  __shared__ __align__(16) float Al[32][68];
  __shared__ __align__(16) float Bl[32][128];
  const int tid = threadIdx.x;
  const int tx = tid & 15, ty = tid >> 4;
  const int m0 = blockIdx.x * 64, n0 = blockIdx.y * 128;

  float acc[4][8];
#pragma unroll
  for (int i=0;i<4;i++)
#pragma unroll
    for (int j=0;j<8;j++) acc[i][j] = 0.f;

  float4 ra[2], rb[4];
  auto gload = [&](int kc){
#pragma unroll
    for (int p=0;p<2;p++){
      int e = tid + (p<<8);
      int arow = e >> 3, akq = (e & 7) << 2;
      ra[p] = *(const float4*)&Ain[(size_t)(m0+arow)*512 + kc + akq];
    }
#pragma unroll
    for (int p=0;p<4;p++){
      int e = tid + (p<<8);
      int krow = e >> 5, bnq = (e & 31) << 2;
      rb[p] = *(const float4*)&wproj[(size_t)(kc+krow)*512 + n0 + bnq];
    }
  };

  gload(0);
  for (int kc=0; kc<512; kc+=32){
    __syncthreads();
#pragma unroll
    for (int p=0;p<2;p++){
      int e = tid + (p<<8);
      int arow = e>>3, akq = (e&7)<<2;
      Al[akq+0][arow] = ra[p].x;
      Al[akq+1][arow] = ra[p].y;
      Al[akq+2][arow] = ra[p].z;
      Al[akq+3][arow] = ra[p].w;
    }
#pragma unroll
    for (int p=0;p<4;p++){
      int e = tid + (p<<8);
      int krow = e>>5, bnq = (e&31)<<2;
      *(float4*)&Bl[krow][bnq] = rb[p];
    }
    __syncthreads();
    if (kc < 480) gload(kc+32);
#pragma unroll
    for (int kk=0; kk<32; ++kk){
      float a[4], b[8];
      *(float4*)&a[0] = *(const float4*)&Al[kk][ty<<2];
      *(float4*)&b[0] = *(const float4*)&Bl[kk][tx<<2];
      *(float4*)&b[4] = *(const float4*)&Bl[kk][64 + (tx<<2)];
#pragma unroll
      for (int i=0;i<4;i++)
#pragma unroll
        for (int j=0;j<8;j++) acc[i][j] = fmaf(a[i], b[j], acc[i][j]);
    }
  }

#pragma unroll
  for (int cj=0; cj<2; cj++){
    float4 bq = *(const float4*)&bproj[n0 + (cj<<6) + (tx<<2)];
#pragma unroll
    for (int i=0;i<4;i++){
      int m = m0 + (ty<<2) + i;
      float4 v4;
      v4.x = acc[i][(cj<<2)+0] + bq.x;
      v4.y = acc[i][(cj<<2)+1] + bq.y;
      v4.z = acc[i][(cj<<2)+2] + bq.z;
      v4.w = acc[i][(cj<<2)+3] + bq.w;
      *(float4*)&outp[(size_t)m*512 + n0 + (cj<<6) + (tx<<2)] = v4;
    }
  }
}

extern "C" void kernel_launch(void* const* d_in, const int* in_sizes, int n_in,
                              void* d_out, int out_size, void* d_ws, size_t ws_size,
                              hipStream_t stream)
{
  const float* x     = (const float*)d_in[0];
  const float* wqkv  = (const float*)d_in[1];
  const float* bqkv  = (const float*)d_in[2];
  const float* wproj = (const float*)d_in[3];
  const float* bproj = (const float*)d_in[4];

  float* out  = (float*)d_out;               // (2,2048,512)
  float* attn = out + 2097152;               // (2,8,2048,2048)

  // ws layout: V, AO, FI, Qf, Kf (fp32) | Khi (fp16)  ~= 36.2 MB
  float* ws = (float*)d_ws;
  float* V   = ws;
  float* AO  = V  + 2097152;
  float* FI  = AO + 2097152;
  float* Qf  = FI + 32768;
  float* Kf  = Qf + 2097152;
  _Float16* Khi = (_Float16*)(Kf + 2097152);

  qkv_kernel <<<dim3(32,12), 256, 0, stream>>>(x, wqkv, bqkv, Qf, Kf, Khi, V, FI);
  attn_kernel<<<2048,        256, 0, stream>>>(Qf, Kf, Khi, V, FI, attn, AO);
  proj_kernel<<<dim3(64,4),  256, 0, stream>>>(AO, wproj, bproj, out);
}

// Round 8
// 582.942 us; speedup vs baseline: 1.3729x; 1.0459x over previous
//
#include <hip/hip_runtime.h>

#define S_  2048
#define HD_ 64
#define NH_ 8
#define MARGIN 4e-3f

typedef _Float16 half8 __attribute__((ext_vector_type(8)));
typedef _Float16 half4v __attribute__((ext_vector_type(4)));
typedef float    f32x4 __attribute__((ext_vector_type(4)));

// 2nd smallest of 4 == 3rd largest counting multiplicity (matches top_k[-1] + >= semantics)
__device__ __forceinline__ float snd_smallest4(float a, float b, float c, float d){
  float lo1 = fminf(a,b), hi1 = fmaxf(a,b);
  float lo2 = fminf(c,d), hi2 = fmaxf(c,d);
  return fminf(fmaxf(lo1,lo2), fminf(hi1,hi2));
}

// exact fp32 dot, R3-validated summation order (d ascending, paired FMA chain)
// qrow is pre-scaled by 0.125 -> result = q.k/8
__device__ __forceinline__ float dot64(const float* __restrict__ qrow,
                                       const float* __restrict__ kcol){
  float acc = 0.f;
#pragma unroll
  for (int dp=0; dp<32; ++dp){
    float2 k2 = *(const float2*)(kcol + 2*dp);
    acc = fmaf(qrow[2*dp+1], k2.y, fmaf(qrow[2*dp], k2.x, acc));
  }
  return acc;
}

// =================== w_proj transpose + fp16 2-plane split: Wh/Wl[n][k] ===================
__global__ __launch_bounds__(256)
void wprep_kernel(const float* __restrict__ wproj,
                  _Float16* __restrict__ Wh, _Float16* __restrict__ Wl)
{
  __shared__ float t[64][65];
  const int k0 = (blockIdx.x >> 3) << 6;
  const int n0 = (blockIdx.x & 7) << 6;
  const int tx = threadIdx.x & 63, ty = threadIdx.x >> 6;
#pragma unroll
  for (int p=0;p<16;p++){
    int kr = ty + (p<<2);
    t[kr][tx] = wproj[(size_t)(k0+kr)*512 + n0 + tx];
  }
  __syncthreads();
#pragma unroll
  for (int p=0;p<16;p++){
    int nr = ty + (p<<2);
    float v = t[tx][nr];
    _Float16 h = (_Float16)v;
    _Float16 lo = (_Float16)((v - (float)h)*2048.0f);
    Wh[(size_t)(n0+nr)*512 + k0 + tx] = h;
    Wl[(size_t)(n0+nr)*512 + k0 + tx] = lo;
  }
}

// =================== QKV GEMM: x(4096x512) @ w(512x1536) -> Qf/Kf/Khi/V/FI ===================
__global__ __launch_bounds__(256, 2)
void qkv_kernel(const float* __restrict__ x, const float* __restrict__ wqkv,
                const float* __restrict__ bqkv,
                float* __restrict__ Qf, float* __restrict__ Kf,
                _Float16* __restrict__ Khi,
                float* __restrict__ V, float* __restrict__ FI)
{
  __shared__ __align__(16) float Al[32][132];   // [k][m]
  __shared__ __align__(16) float Bl[32][128];   // [k][n]
  const int tid = threadIdx.x;
  const int tx = tid & 15, ty = tid >> 4;
  const int m0 = blockIdx.x * 128, n0 = blockIdx.y * 128;

  float acc[8][8];
#pragma unroll
  for (int i=0;i<8;i++)
#pragma unroll
    for (int j=0;j<8;j++) acc[i][j] = 0.f;

  float4 ra[4], rb[4];
  auto gload = [&](int kc){
#pragma unroll
    for (int p=0;p<4;p++){
      int e = tid + (p<<8);
      int arow = e >> 3, akq = (e & 7) << 2;
      ra[p] = *(const float4*)&x[(size_t)(m0+arow)*512 + kc + akq];
      int krow = e >> 5, bnq = (e & 31) << 2;
      rb[p] = *(const float4*)&wqkv[(size_t)(kc+krow)*1536 + n0 + bnq];
    }
  };

  gload(0);
  for (int kc=0; kc<512; kc+=32){
    __syncthreads();
#pragma unroll
    for (int p=0;p<4;p++){
      int e = tid + (p<<8);
      int arow = e>>3, akq = (e&7)<<2;
      Al[akq+0][arow] = ra[p].x;
      Al[akq+1][arow] = ra[p].y;
      Al[akq+2][arow] = ra[p].z;
      Al[akq+3][arow] = ra[p].w;
      int krow = e>>5, bnq = (e&31)<<2;
      *(float4*)&Bl[krow][bnq] = rb[p];
    }
    __syncthreads();
    if (kc < 480) gload(kc+32);
#pragma unroll
    for (int kk=0; kk<32; ++kk){
      float a[8], b[8];
      *(float4*)&a[0] = *(const float4*)&Al[kk][ty<<2];
      *(float4*)&a[4] = *(const float4*)&Al[kk][64 + (ty<<2)];
      *(float4*)&b[0] = *(const float4*)&Bl[kk][tx<<2];
      *(float4*)&b[4] = *(const float4*)&Bl[kk][64 + (tx<<2)];
#pragma unroll
      for (int i=0;i<8;i++)
#pragma unroll
        for (int j=0;j<8;j++) acc[i][j] = fmaf(a[i], b[j], acc[i][j]);
    }
  }

  // epilogue: each 64-col group is uniformly one head of Q, K or V (all stores coalesced)
#pragma unroll
  for (int cj=0; cj<2; cj++){
    int nb = n0 + (cj<<6);
    int which = nb >> 9;           // 0:Q 1:K 2:V
    int h = (nb >> 6) & 7;
    float4 bq = *(const float4*)&bqkv[nb + (tx<<2)];
#pragma unroll
    for (int ri=0; ri<2; ri++)
#pragma unroll
      for (int i=0;i<4;i++){
        int m = m0 + (ri<<6) + (ty<<2) + i;
        int bb = m >> 11, s = m & 2047;
        float4 v4;
        v4.x = acc[(ri<<2)+i][(cj<<2)+0] + bq.x;
        v4.y = acc[(ri<<2)+i][(cj<<2)+1] + bq.y;
        v4.z = acc[(ri<<2)+i][(cj<<2)+2] + bq.z;
        v4.w = acc[(ri<<2)+i][(cj<<2)+3] + bq.w;
        size_t base = (((size_t)bb*NH_ + h)*S_ + s)*HD_ + (tx<<2);
        if (which == 2){
          *(float4*)&V[base] = v4;
        } else if (which == 0){
          *(float4*)&Qf[base] = v4;
          float fs = v4.x + v4.y + v4.z + v4.w;
#pragma unroll
          for (int st=1; st<16; st<<=1) fs += __shfl_xor(fs, st);
          if (tx == 0)
            FI[((size_t)bb*NH_ + h)*S_ + s] = 1.0f / (1.0f + expf(-fs * (1.0f/64.0f)));
        } else {
          *(float4*)&Kf[base] = v4;
          half4v hv;
          hv[0] = (_Float16)(v4.x * 16.0f);
          hv[1] = (_Float16)(v4.y * 16.0f);
          hv[2] = (_Float16)(v4.z * 16.0f);
          hv[3] = (_Float16)(v4.w * 16.0f);
          *(half4v*)&Khi[base] = hv;
        }
      }
  }
}

// =================== fused attention: two-pass MFMA prune -> exact fp32 selection ===================
#define CE(x,y){ float mx_=fmaxf(x,y), mn_=fminf(x,y); x=mx_; y=mn_; }
#define SORT5(t0,t1,t2,t3,t4) \
    CE(t0,t1) CE(t3,t4) CE(t2,t4) CE(t2,t3) CE(t1,t4) \
    CE(t0,t3) CE(t0,t2) CE(t1,t3) CE(t1,t2)
#define MERGE5(a0,a1,a2,a3,a4,b0,b1,b2,b3,b4) { \
    a0 = fmaxf(a0,b4); a1 = fmaxf(a1,b3); a2 = fmaxf(a2,b2); \
    a3 = fmaxf(a3,b1); a4 = fmaxf(a4,b0); \
    SORT5(a0,a1,a2,a3,a4) }
// insert v into sorted-desc t0..t4 (multiset top-5, 9 ops, unconditional)
#define INS5(t0,t1,t2,t3,t4,v){ \
    float r0_ = fminf(t0, v); t0 = fmaxf(t0, v); \
    float r1_ = fminf(t1, r0_); t1 = fmaxf(t1, r0_); \
    float r2_ = fminf(t2, r1_); t2 = fmaxf(t2, r1_); \
    float r3_ = fminf(t3, r2_); t3 = fmaxf(t3, r2_); \
    t4 = fmaxf(t4, r3_); }

__global__ __launch_bounds__(256, 4)
void attn_kernel(const float* __restrict__ Qf, const float* __restrict__ Kf,
                 const _Float16* __restrict__ Khi,
                 const float* __restrict__ V, const float* __restrict__ FI,
                 float* __restrict__ attn,
                 _Float16* __restrict__ AOh, _Float16* __restrict__ AOl)
{
  __shared__ __align__(16) float qsl[16*64];   // q rows, pre-scaled 0.125
  __shared__ float diag[16][24];               // EXACT window scores
  __shared__ float wtop[4][16][5];             // approx per-wave top5
  __shared__ float tgA[16];                    // approx thr_g
  __shared__ int   ccnt[16];
  __shared__ int   ccol[16][32];
  __shared__ float cex[16][32];

  const int tid  = threadIdx.x;
  const int w    = tid >> 6, l = tid & 63;
  const int quad = l >> 4, ln = l & 15;
  const int head = blockIdx.x >> 7;
  const int r0   = (blockIdx.x & 127) << 4;
  const int cb   = w << 9;               // wave's 512-col window

  if (tid < 16) ccnt[tid] = 0;

  float* attnh = attn + (size_t)head*S_*S_;

  // ---- zero-fill this block's 16 attn rows (wave w owns rows 4w..4w+3) ----
  {
    const float4 z4 = {0.f,0.f,0.f,0.f};
    float4* zp = (float4*)(attnh + (size_t)(r0 + (w<<2))*S_) + l;
#pragma unroll
    for (int rr=0;rr<4;rr++)
#pragma unroll
      for (int i=0;i<8;i++)
        zp[rr*512 + i*64] = z4;
  }

  // ---- stage q rows (scaled 0.125, exact pow2) ----
  {
    const float4* qg = (const float4*)(Qf + ((size_t)head*S_ + r0)*HD_);
    float4 q4 = qg[tid];
    q4.x *= 0.125f; q4.y *= 0.125f; q4.z *= 0.125f; q4.w *= 0.125f;
    ((float4*)qsl)[tid] = q4;
  }
  __syncthreads();

  // ---- A-fragments (hi plane): A[m=ln][k=quad*8+j (+32)] ----
  half8 a_h0, a_h1;
#pragma unroll
  for (int j=0;j<8;j++){
    a_h0[j] = (_Float16)(qsl[ln*HD_ + quad*8 + j] * 128.0f);
    a_h1[j] = (_Float16)(qsl[ln*HD_ + quad*8 + j + 32] * 128.0f);
  }

  const _Float16* kh = Khi + (size_t)head*S_*HD_;
  const float*    kf = Kf  + (size_t)head*S_*HD_;

  // ---- pass 1: stream tiles, keep per-row top5 in regs (no score caching) ----
  float t5[4][5];
#pragma unroll
  for (int g=0;g<4;g++)
#pragma unroll
    for (int k=0;k<5;k++) t5[g][k] = -INFINITY;

#pragma unroll 4
  for (int t=0; t<32; ++t){
    size_t boff = (size_t)(cb + (t<<4) + ln)*HD_ + quad*8;
    half8 bh0 = *(const half8*)(kh + boff);
    half8 bh1 = *(const half8*)(kh + boff + 32);
    f32x4 a4 = {0.f,0.f,0.f,0.f};
    a4 = __builtin_amdgcn_mfma_f32_16x16x32_f16(a_h0, bh0, a4, 0,0,0);
    a4 = __builtin_amdgcn_mfma_f32_16x16x32_f16(a_h1, bh1, a4, 0,0,0);
#pragma unroll
    for (int g=0; g<4; ++g){
      float v = a4[g] * 0x1p-11f;
      INS5(t5[g][0],t5[g][1],t5[g][2],t5[g][3],t5[g][4], v)
    }
  }

  // butterfly-merge top5 across the 16 ln lanes, then stash per-wave
#pragma unroll
  for (int g=0; g<4; ++g){
    float a0=t5[g][0], a1=t5[g][1], a2=t5[g][2], a3=t5[g][3], a4=t5[g][4];
#pragma unroll
    for (int st=1; st<16; st<<=1){
      float b0 = __shfl_xor(a4, st);
      float b1 = __shfl_xor(a3, st);
      float b2 = __shfl_xor(a2, st);
      float b3 = __shfl_xor(a1, st);
      float b4 = __shfl_xor(a0, st);
      MERGE5(a0,a1,a2,a3,a4, b4,b3,b2,b1,b0)
    }
    if (ln == 0){
      int row = (quad<<2) + g;
      wtop[w][row][0]=a0; wtop[w][row][1]=a1; wtop[w][row][2]=a2;
      wtop[w][row][3]=a3; wtop[w][row][4]=a4;
    }
  }
  __syncthreads();

  if (tid < 16){
    float m5[5] = {-INFINITY,-INFINITY,-INFINITY,-INFINITY,-INFINITY};
    for (int ww=0; ww<4; ww++)
      for (int k=0;k<5;k++){
        float v = wtop[ww][tid][k];
        float b0 = fminf(m5[0], v); m5[0] = fmaxf(m5[0], v);
        float b1 = fminf(m5[1], b0); m5[1] = fmaxf(m5[1], b0);
        float b2 = fminf(m5[2], b1); m5[2] = fmaxf(m5[2], b1);
        float b3 = fminf(m5[3], b2); m5[3] = fmaxf(m5[3], b2);
        m5[4] = fmaxf(m5[4], b3);
      }
    tgA[tid] = m5[4];
  }
  __syncthreads();

  // ---- pass 2: recompute tiles (bit-identical) + gather candidates ----
  {
    float thr[4];
#pragma unroll
    for (int g=0;g<4;g++) thr[g] = tgA[(quad<<2)+g] - MARGIN;
#pragma unroll 4
    for (int t=0; t<32; ++t){
      size_t boff = (size_t)(cb + (t<<4) + ln)*HD_ + quad*8;
      half8 bh0 = *(const half8*)(kh + boff);
      half8 bh1 = *(const half8*)(kh + boff + 32);
      f32x4 a4 = {0.f,0.f,0.f,0.f};
      a4 = __builtin_amdgcn_mfma_f32_16x16x32_f16(a_h0, bh0, a4, 0,0,0);
      a4 = __builtin_amdgcn_mfma_f32_16x16x32_f16(a_h1, bh1, a4, 0,0,0);
#pragma unroll
      for (int g=0; g<4; ++g){
        float v = a4[g] * 0x1p-11f;
        if (v >= thr[g]){
          int row = (quad<<2) + g;
          int c = cb + (t<<4) + ln;
          int slot = atomicAdd(&ccnt[row], 1);
          if (slot < 32) ccol[row][slot] = c;
        }
      }
    }
  }

  // ---- EXACT diag (window cols [Lo, Lo+24)) via scalar fp32 dots ----
  const int Lo = (r0 >= 4) ? (r0 - 4) : 0;
  {
    int row = tid >> 4, j = tid & 15;
    int c0 = Lo + j;
    if (c0 < S_) diag[row][j] = dot64(qsl + row*HD_, kf + (size_t)c0*HD_);
    if (j < 8){
      int c1 = Lo + 16 + j;
      if (c1 < S_) diag[row][16+j] = dot64(qsl + row*HD_, kf + (size_t)c1*HD_);
    }
  }
  __syncthreads();

  // ---- EXACT rescore of candidates ----
  {
    int row = tid >> 4, j = tid & 15;
    int n = ccnt[row]; if (n > 32) n = 32;
    if (j < n)      cex[row][j]    = dot64(qsl + row*HD_, kf + (size_t)ccol[row][j]*HD_);
    if (j + 16 < n) cex[row][j+16] = dot64(qsl + row*HD_, kf + (size_t)ccol[row][j+16]*HD_);
  }
  __syncthreads();

  // ---- exact selection + softmax (serial per row; all values exact fp32) ----
  if (tid < 16){
    int n = ccnt[tid]; if (n > 32) n = 32;
    float m5[5] = {-INFINITY,-INFINITY,-INFINITY,-INFINITY,-INFINITY};
    for (int i=0;i<n;i++){
      float v = cex[tid][i];
      float b0 = fminf(m5[0], v); m5[0] = fmaxf(m5[0], v);
      float b1 = fminf(m5[1], b0); m5[1] = fmaxf(m5[1], b0);
      float b2 = fminf(m5[2], b1); m5[2] = fmaxf(m5[2], b1);
      float b3 = fminf(m5[3], b2); m5[3] = fmaxf(m5[3], b2);
      m5[4] = fmaxf(m5[4], b3);
    }
    float tg = m5[4], mx = m5[0];
    int R = r0 + tid;
    int b = R & ~1; if (b > 2044) b = 2044;
    float tb = snd_smallest4(diag[tid][b-Lo], diag[tid][b+1-Lo],
                             diag[tid][b+2-Lo], diag[tid][b+3-Lo]);
    float ta = -INFINITY;
    if (b >= 2 && (R - b) <= 1){
      int a0i = b - 2;
      ta = snd_smallest4(diag[tid][a0i-Lo], diag[tid][a0i+1-Lo],
                         diag[tid][a0i+2-Lo], diag[tid][a0i+3-Lo]);
    }
    float Z = 0.f; int k = 0;
    for (int i=0;i<n;i++){
      float s = cex[tid][i]; int c = ccol[tid][i];
      bool inb = (unsigned)(c - b) < 4u;
      bool ina = (unsigned)(c - (b-2)) < 2u;
      float lt = inb ? tb : (ina ? ta : -INFINITY);
      if (s >= tg && s >= lt){
        float p = expf(s - mx);
        Z += p;
        ccol[tid][k] = c; cex[tid][k] = p; k++;
      }
    }
    float inv = 1.0f / Z;
    for (int i=0;i<k;i++) cex[tid][i] *= inv;   // normalized attn weights
    ccnt[tid] = k;
  }
  __syncthreads();

  // ---- scatter normalized nonzeros (wave w owns rows 4w..4w+3) ----
#pragma unroll
  for (int rr=0;rr<4;rr++){
    int r = (w<<2) + rr;
    size_t rowb = (size_t)(r0 + r) * S_;
    int n = ccnt[r];
    for (int s2 = l; s2 < n; s2 += 64)
      attnh[rowb + ccol[r][s2]] = cex[r][s2];
  }

  // ---- sparse out = sum attn * v * fi -> AO fp16 hi/lo planes ----
  const float* vh  = V  + (size_t)head*S_*HD_;
  const float* fih = FI + (size_t)head*S_;
  const int bb = head >> 3, hh = head & 7;
#pragma unroll
  for (int rr=0;rr<4;rr++){
    int r = (w<<2) + rr;
    int n = ccnt[r];
    float o = 0.f;
    for (int i=0;i<n;i++){
      int c = ccol[r][i];
      float av = cex[r][i] * fih[c];
      o = fmaf(av, vh[(size_t)c*HD_ + l], o);
    }
    size_t oidx = (((size_t)bb*S_ + (r0+r))*NH_ + hh)*HD_ + l;
    _Float16 oh = (_Float16)o;
    _Float16 ol = (_Float16)((o - (float)oh) * 2048.0f);
    AOh[oidx] = oh;
    AOl[oidx] = ol;
  }
}
#undef CE
#undef SORT5
#undef MERGE5
#undef INS5

// =================== proj GEMM via fp16-split MFMA: out = AO @ w_proj + b ===================
// block: rows r0..r0+15, cols blockIdx.y*256 + w*64 .. +63 (4 n-tiles of 16). grid (256,2).
__global__ __launch_bounds__(256)
void proj_kernel(const _Float16* __restrict__ AOh, const _Float16* __restrict__ AOl,
                 const _Float16* __restrict__ Wh, const _Float16* __restrict__ Wl,
                 const float* __restrict__ bproj, float* __restrict__ outp)
{
  const int tid = threadIdx.x;
  const int w = tid >> 6, l = tid & 63;
  const int quad = l >> 4, ln = l & 15;
  const int r0 = blockIdx.x << 4;
  const int nb = (blockIdx.y << 8) + (w << 6);

  f32x4 accA[4], accB[4];
#pragma unroll
  for (int nt=0;nt<4;nt++){
    accA[nt] = (f32x4){0.f,0.f,0.f,0.f};
    accB[nt] = (f32x4){0.f,0.f,0.f,0.f};
  }

  const _Float16* ah = AOh + (size_t)(r0+ln)*512 + quad*8;
  const _Float16* al = AOl + (size_t)(r0+ln)*512 + quad*8;

#pragma unroll 4
  for (int kc=0; kc<16; ++kc){
    half8 a_h = *(const half8*)(ah + (kc<<5));
    half8 a_l = *(const half8*)(al + (kc<<5));
#pragma unroll
    for (int nt=0; nt<4; ++nt){
      size_t bo = (size_t)(nb + (nt<<4) + ln)*512 + (kc<<5) + quad*8;
      half8 b_h = *(const half8*)(Wh + bo);
      half8 b_l = *(const half8*)(Wl + bo);
      accA[nt] = __builtin_amdgcn_mfma_f32_16x16x32_f16(a_h, b_h, accA[nt], 0,0,0);
      accB[nt] = __builtin_amdgcn_mfma_f32_16x16x32_f16(a_h, b_l, accB[nt], 0,0,0);
      accB[nt] = __builtin_amdgcn_mfma_f32_16x16x32_f16(a_l, b_h, accB[nt], 0,0,0);
    }
  }

#pragma unroll
  for (int nt=0; nt<4; ++nt){
    int n = nb + (nt<<4) + ln;
    float bias = bproj[n];
#pragma unroll
    for (int g=0; g<4; ++g){
      int m = r0 + (quad<<2) + g;
      outp[(size_t)m*512 + n] = accA[nt][g] + accB[nt][g]*0x1p-11f + bias;
    }
  }
}

extern "C" void kernel_launch(void* const* d_in, const int* in_sizes, int n_in,
                              void* d_out, int out_size, void* d_ws, size_t ws_size,
                              hipStream_t stream)
{
  const float* x     = (const float*)d_in[0];
  const float* wqkv  = (const float*)d_in[1];
  const float* bqkv  = (const float*)d_in[2];
  const float* wproj = (const float*)d_in[3];
  const float* bproj = (const float*)d_in[4];

  float* out  = (float*)d_out;               // (2,2048,512)
  float* attn = out + 2097152;               // (2,8,2048,2048)

  // ws layout: V, FI, Qf, Kf (fp32) | Khi, AOh, AOl, Wh, Wl (fp16)  ~= 39 MB
  float* ws = (float*)d_ws;
  float* V   = ws;
  float* FI  = V  + 2097152;
  float* Qf  = FI + 32768;
  float* Kf  = Qf + 2097152;
  _Float16* Khi = (_Float16*)(Kf + 2097152);
  _Float16* AOh = Khi + 2097152;
  _Float16* AOl = AOh + 2097152;
  _Float16* Wh  = AOl + 2097152;
  _Float16* Wl  = Wh  + 262144;

  wprep_kernel<<<64,          256, 0, stream>>>(wproj, Wh, Wl);
  qkv_kernel  <<<dim3(32,12), 256, 0, stream>>>(x, wqkv, bqkv, Qf, Kf, Khi, V, FI);
  attn_kernel <<<2048,        256, 0, stream>>>(Qf, Kf, Khi, V, FI, attn, AOh, AOl);
  proj_kernel <<<dim3(256,2), 256, 0, stream>>>(AOh, AOl, Wh, Wl, bproj, out);
}